// Round 1
// baseline (9026.552 us; speedup 1.0000x reference)
//
#include <hip/hip_runtime.h>
#include <math.h>

#define EPS_NORM 1e-5f
#define EPS_VAR  1e-9f

// ---------------------------------------------------------------------------
// Stage 1: per-(batch, channel) sum / sumsq over spatial axis (split-N atomic)
// x layout: (B, N, Cn) channel-last. Block = 256 threads, one channel each.
// ---------------------------------------------------------------------------
__global__ void __launch_bounds__(256) stat_partial(
    const float* __restrict__ x, float* __restrict__ sum, float* __restrict__ sumsq,
    int N, int Cn, int chG, int nG, int nPer)
{
    int bx = blockIdx.x;
    int b  = bx / (chG * nG);
    int r  = bx % (chG * nG);
    int cg = r / nG;
    int ng = r % nG;
    int ch = cg * 256 + threadIdx.x;
    if (ch >= Cn) return;
    int n0 = ng * nPer;
    int n1 = min(n0 + nPer, N);
    const float* p = x + (long)(b * N) * Cn + ch;
    float s = 0.f, ss = 0.f;
    for (int n = n0; n < n1; ++n) {
        float v = p[(long)n * Cn];
        s += v;
        ss = fmaf(v, v, ss);
    }
    atomicAdd(&sum[b * Cn + ch], s);
    atomicAdd(&sumsq[b * Cn + ch], ss);
}

// In-place: sum -> mean, sumsq -> rstd
__global__ void __launch_bounds__(256) stat_finalize(
    float* __restrict__ sum, float* __restrict__ sumsq, int total, float invN)
{
    int i = blockIdx.x * blockDim.x + threadIdx.x;
    if (i >= total) return;
    float m = sum[i] * invN;
    float v = sumsq[i] * invN - m * m;
    sum[i]   = m;
    sumsq[i] = rsqrtf(v + EPS_NORM);
}

// ---------------------------------------------------------------------------
// Stage 2: flash-style fused attention + AAT + MSE partial.
// CCL = Cc/64 (q/k channels per lane), CL = C/64 (v channels per lane),
// NQ = query rows per wave. Block = 4 waves => 4*NQ rows per block.
// Q = comb_c tensor, K = comb_s tensor, V = style, CT = content, CS = target.
// Normalization of q/k applied on load using precomputed mean/rstd.
// ---------------------------------------------------------------------------
template<int CCL, int CL, int NQ>
__global__ void __launch_bounds__(256) flash_aat(
    const float* __restrict__ Q, const float* __restrict__ K, const float* __restrict__ V,
    const float* __restrict__ CT, const float* __restrict__ CS,
    const float* __restrict__ qmean, const float* __restrict__ qrstd,
    const float* __restrict__ kmean, const float* __restrict__ krstd,
    const float* __restrict__ cmean, const float* __restrict__ crstd,
    float* __restrict__ loss, int N)
{
    constexpr int CC   = CCL * 64;
    constexpr int C    = CL * 64;
    constexpr int ROWS = 4 * NQ;
    const int lane = threadIdx.x & 63;
    const int wave = threadIdx.x >> 6;
    const int rowBlocks = N / ROWS;
    const int b  = blockIdx.x / rowBlocks;
    const int rb = blockIdx.x % rowBlocks;
    const int i0 = rb * ROWS + wave * NQ;

    // Per-lane key-side stats (channels lane + 64t are fixed per lane)
    float kmu[CCL], krs[CCL];
#pragma unroll
    for (int t = 0; t < CCL; ++t) {
        int ch = lane + 64 * t;
        kmu[t] = kmean[b * CC + ch];
        krs[t] = krstd[b * CC + ch];
    }

    // Preload normalized query rows
    float q[NQ][CCL];
#pragma unroll
    for (int qi = 0; qi < NQ; ++qi) {
        long base = (long)(b * N + i0 + qi) * CC;
#pragma unroll
        for (int t = 0; t < CCL; ++t) {
            int ch = lane + 64 * t;
            q[qi][t] = (Q[base + ch] - qmean[b * CC + ch]) * qrstd[b * CC + ch];
        }
    }

    float mval[NQ], lsum[NQ];
    float Macc[NQ][CL], Sacc[NQ][CL];
#pragma unroll
    for (int qi = 0; qi < NQ; ++qi) {
        mval[qi] = -1e30f;
        lsum[qi] = 0.f;
#pragma unroll
        for (int t = 0; t < CL; ++t) { Macc[qi][t] = 0.f; Sacc[qi][t] = 0.f; }
    }

    for (int j = 0; j < N; ++j) {
        long kb = (long)(b * N + j) * CC;
        float dot[NQ];
#pragma unroll
        for (int qi = 0; qi < NQ; ++qi) dot[qi] = 0.f;
#pragma unroll
        for (int t = 0; t < CCL; ++t) {
            float kv = (K[kb + lane + 64 * t] - kmu[t]) * krs[t];
#pragma unroll
            for (int qi = 0; qi < NQ; ++qi) dot[qi] = fmaf(q[qi][t], kv, dot[qi]);
        }
        // 64-lane butterfly: all lanes end with identical sums (wave-uniform)
#pragma unroll
        for (int off = 32; off > 0; off >>= 1) {
#pragma unroll
            for (int qi = 0; qi < NQ; ++qi) dot[qi] += __shfl_xor(dot[qi], off, 64);
        }

        long vb = (long)(b * N + j) * C;
        float vv[CL];
#pragma unroll
        for (int t = 0; t < CL; ++t) vv[t] = V[vb + lane + 64 * t];

#pragma unroll
        for (int qi = 0; qi < NQ; ++qi) {
            float s = dot[qi];
            float p;
            if (s > mval[qi]) {             // wave-uniform branch
                float corr = __expf(mval[qi] - s);
                lsum[qi] *= corr;
#pragma unroll
                for (int t = 0; t < CL; ++t) { Macc[qi][t] *= corr; Sacc[qi][t] *= corr; }
                mval[qi] = s;
                p = 1.f;
            } else {
                p = __expf(s - mval[qi]);
            }
            lsum[qi] += p;
#pragma unroll
            for (int t = 0; t < CL; ++t) {
                float pv = p * vv[t];
                Macc[qi][t] += pv;
                Sacc[qi][t] = fmaf(pv, vv[t], Sacc[qi][t]);
            }
        }
    }

    // Epilogue: M, S, norm_content, MSE partial
    float acc = 0.f;
#pragma unroll
    for (int qi = 0; qi < NQ; ++qi) {
        float inv_l = 1.f / lsum[qi];
        long base = (long)(b * N + i0 + qi) * C;
#pragma unroll
        for (int t = 0; t < CL; ++t) {
            int ch = lane + 64 * t;
            float M  = Macc[qi][t] * inv_l;
            float S2 = Sacc[qi][t] * inv_l - M * M;
            float S  = sqrtf(fmaxf(S2, EPS_VAR));
            float nc = (CT[base + ch] - cmean[b * C + ch]) * crstd[b * C + ch];
            float d  = CS[base + ch] - (S * nc + M);
            acc = fmaf(d, d, acc);
        }
    }
#pragma unroll
    for (int off = 32; off > 0; off >>= 1) acc += __shfl_xor(acc, off, 64);
    if (lane == 0) atomicAdd(loss, acc);
}

__global__ void combine_loss(const float* __restrict__ lp, float* __restrict__ out,
                             float s0, float s1, float s2)
{
    out[0] = lp[0] * s0 + lp[1] * s1 + lp[2] * s2;
}

// ---------------------------------------------------------------------------
extern "C" void kernel_launch(void* const* d_in, const int* in_sizes, int n_in,
                              void* d_out, int out_size, void* d_ws, size_t ws_size,
                              hipStream_t stream)
{
    const float* cs2 = (const float*)d_in[0];
    const float* c2  = (const float*)d_in[1];
    const float* s2v = (const float*)d_in[2];
    const float* cc2 = (const float*)d_in[3];
    const float* sc2 = (const float*)d_in[4];
    const float* cs3 = (const float*)d_in[5];
    const float* c3  = (const float*)d_in[6];
    const float* s3v = (const float*)d_in[7];
    const float* cc3 = (const float*)d_in[8];
    const float* sc3 = (const float*)d_in[9];
    const float* cs4 = (const float*)d_in[10];
    const float* c4  = (const float*)d_in[11];
    const float* s4v = (const float*)d_in[12];
    const float* cc4 = (const float*)d_in[13];
    const float* sc4 = (const float*)d_in[14];

    const int B = 4;
    float* ws = (float*)d_ws;
    size_t off = 0;
    auto alloc = [&](size_t n) { float* p = ws + off; off += n; return p; };

    float* lossp = alloc(4);
    float* c2m = alloc(B * 256);  float* c2r = alloc(B * 256);
    float* q2m = alloc(B * 448);  float* q2r = alloc(B * 448);
    float* k2m = alloc(B * 448);  float* k2r = alloc(B * 448);
    float* c3m = alloc(B * 512);  float* c3r = alloc(B * 512);
    float* q3m = alloc(B * 960);  float* q3r = alloc(B * 960);
    float* k3m = alloc(B * 960);  float* k3r = alloc(B * 960);
    float* c4m = alloc(B * 512);  float* c4r = alloc(B * 512);
    float* q4m = alloc(B * 1472); float* q4r = alloc(B * 1472);
    float* k4m = alloc(B * 1472); float* k4r = alloc(B * 1472);

    // zero the accumulator region (ws is poisoned 0xAA before every launch)
    hipMemsetAsync(d_ws, 0, off * sizeof(float), stream);

    auto stats = [&](const float* x, float* sm, float* sq, int N, int Cn) {
        int chG  = (Cn + 255) / 256;
        int nPer = 256;
        int nG   = (N + nPer - 1) / nPer;
        hipLaunchKernelGGL(stat_partial, dim3(B * chG * nG), dim3(256), 0, stream,
                           x, sm, sq, N, Cn, chG, nG, nPer);
        int total = B * Cn;
        hipLaunchKernelGGL(stat_finalize, dim3((total + 255) / 256), dim3(256), 0, stream,
                           sm, sq, total, 1.0f / (float)N);
    };

    stats(c2,  c2m, c2r, 4096, 256);
    stats(cc2, q2m, q2r, 4096, 448);
    stats(sc2, k2m, k2r, 4096, 448);
    stats(c3,  c3m, c3r, 1024, 512);
    stats(cc3, q3m, q3r, 1024, 960);
    stats(sc3, k3m, k3r, 1024, 960);
    stats(c4,  c4m, c4r, 256, 512);
    stats(cc4, q4m, q4r, 256, 1472);
    stats(sc4, k4m, k4r, 256, 1472);

    // scale 2: N=4096, Cc=448 (CCL=7), C=256 (CL=4), NQ=4 -> 16 rows/block
    hipLaunchKernelGGL((flash_aat<7, 4, 4>), dim3(B * 4096 / 16), dim3(256), 0, stream,
                       cc2, sc2, s2v, c2, cs2, q2m, q2r, k2m, k2r, c2m, c2r,
                       &lossp[0], 4096);
    // scale 3: N=1024, Cc=960 (CCL=15), C=512 (CL=8), NQ=2 -> 8 rows/block
    hipLaunchKernelGGL((flash_aat<15, 8, 2>), dim3(B * 1024 / 8), dim3(256), 0, stream,
                       cc3, sc3, s3v, c3, cs3, q3m, q3r, k3m, k3r, c3m, c3r,
                       &lossp[1], 1024);
    // scale 4: N=256, Cc=1472 (CCL=23), C=512 (CL=8), NQ=2 -> 8 rows/block
    hipLaunchKernelGGL((flash_aat<23, 8, 2>), dim3(B * 256 / 8), dim3(256), 0, stream,
                       cc4, sc4, s4v, c4, cs4, q4m, q4r, k4m, k4r, c4m, c4r,
                       &lossp[2], 256);

    hipLaunchKernelGGL(combine_loss, dim3(1), dim3(1), 0, stream,
                       lossp, (float*)d_out,
                       1.0f / (4.0f * 4096.0f * 256.0f),
                       1.0f / (4.0f * 1024.0f * 512.0f),
                       1.0f / (4.0f * 256.0f * 512.0f));
}

// Round 2
// 3551.351 us; speedup vs baseline: 2.5417x; 2.5417x over previous
//
#include <hip/hip_runtime.h>
#include <math.h>

#define EPS_NORM 1e-5f
#define EPS_VAR  1e-9f

typedef unsigned short ushort_t;
typedef __attribute__((ext_vector_type(8))) short short8;
typedef __attribute__((ext_vector_type(4))) float f32x4;

#define MFMA16(a, b, c) __builtin_amdgcn_mfma_f32_16x16x32_bf16((a), (b), (c), 0, 0, 0)

// ---------------------------------------------------------------------------
// bf16 helpers (RNE), header-independent
// ---------------------------------------------------------------------------
__device__ inline ushort_t bf16_bits(float x) {
    union { float f; unsigned u; } v; v.f = x;
    unsigned r = v.u + 0x7fffu + ((v.u >> 16) & 1u);
    return (ushort_t)(r >> 16);
}
__device__ inline float bf16_back(ushort_t b) {
    union { unsigned u; float f; } v; v.u = ((unsigned)b) << 16;
    return v.f;
}
__device__ inline uint4 pack8(const ushort_t* s) {
    uint4 r;
    r.x = (unsigned)s[0] | ((unsigned)s[1] << 16);
    r.y = (unsigned)s[2] | ((unsigned)s[3] << 16);
    r.z = (unsigned)s[4] | ((unsigned)s[5] << 16);
    r.w = (unsigned)s[6] | ((unsigned)s[7] << 16);
    return r;
}

// ---------------------------------------------------------------------------
// Stage 1: per-(batch, channel) sum / sumsq over spatial axis (split-N atomic)
// ---------------------------------------------------------------------------
__global__ void __launch_bounds__(256) stat_partial(
    const float* __restrict__ x, float* __restrict__ sum, float* __restrict__ sumsq,
    int N, int Cn, int chG, int nG, int nPer)
{
    int bx = blockIdx.x;
    int b  = bx / (chG * nG);
    int r  = bx % (chG * nG);
    int cg = r / nG;
    int ng = r % nG;
    int ch = cg * 256 + threadIdx.x;
    if (ch >= Cn) return;
    int n0 = ng * nPer;
    int n1 = min(n0 + nPer, N);
    const float* p = x + (long)(b * N) * Cn + ch;
    float s = 0.f, ss = 0.f;
    for (int n = n0; n < n1; ++n) {
        float v = p[(long)n * Cn];
        s += v;
        ss = fmaf(v, v, ss);
    }
    atomicAdd(&sum[b * Cn + ch], s);
    atomicAdd(&sumsq[b * Cn + ch], ss);
}

__global__ void __launch_bounds__(256) stat_finalize(
    float* __restrict__ sum, float* __restrict__ sumsq, int total, float invN)
{
    int i = blockIdx.x * blockDim.x + threadIdx.x;
    if (i >= total) return;
    float m = sum[i] * invN;
    float v = sumsq[i] * invN - m * m;
    sum[i]   = m;
    sumsq[i] = rsqrtf(v + EPS_NORM);
}

// ---------------------------------------------------------------------------
// Prepass: normalize X (B,N,Cn) and split to bf16 hi/lo (same layout)
// ---------------------------------------------------------------------------
__global__ void __launch_bounds__(256) norm_split(
    const float* __restrict__ x, const float* __restrict__ mean,
    const float* __restrict__ rstd,
    ushort_t* __restrict__ hi, ushort_t* __restrict__ lo, int N, int Cn)
{
    int bn = blockIdx.x;          // b*N + n
    int b  = bn / N;
    long base = (long)bn * Cn;
    for (int ch = threadIdx.x; ch < Cn; ch += 256) {
        float v = (x[base + ch] - mean[b * Cn + ch]) * rstd[b * Cn + ch];
        ushort_t h = bf16_bits(v);
        hi[base + ch] = h;
        lo[base + ch] = bf16_bits(v - bf16_back(h));
    }
}

// ---------------------------------------------------------------------------
// Prepass: V (B,N,C) -> transposed (B,C,N) bf16 hi/lo of v and v^2
// grid = B * (C/64) * (N/KSEG); block 256 = 64 ch-lanes x 4 key groups
// ---------------------------------------------------------------------------
template<int KSEG>
__global__ void __launch_bounds__(256) vsplit_t(
    const float* __restrict__ v,
    ushort_t* __restrict__ vthi, ushort_t* __restrict__ vtlo,
    ushort_t* __restrict__ v2thi, ushort_t* __restrict__ v2tlo, int N, int C)
{
    int cPB = C / 64, nSeg = N / KSEG;
    int bid = blockIdx.x;
    int b   = bid / (cPB * nSeg);
    int rem = bid % (cPB * nSeg);
    int cb  = rem / nSeg;
    int ns  = rem % nSeg;
    int ch  = cb * 64 + (threadIdx.x & 63);
    const int KL = KSEG / 4;
    int k0  = ns * KSEG + (threadIdx.x >> 6) * KL;
    long obase = ((long)b * C + ch) * N;
    for (int k = k0; k < k0 + KL; k += 8) {
        ushort_t h8[8], l8[8], h28[8], l28[8];
#pragma unroll
        for (int i = 0; i < 8; ++i) {
            float x  = v[((long)b * N + k + i) * C + ch];
            ushort_t h = bf16_bits(x);
            h8[i] = h;
            l8[i] = bf16_bits(x - bf16_back(h));
            float x2 = x * x;
            ushort_t h2 = bf16_bits(x2);
            h28[i] = h2;
            l28[i] = bf16_bits(x2 - bf16_back(h2));
        }
        *(uint4*)(vthi  + obase + k) = pack8(h8);
        *(uint4*)(vtlo  + obase + k) = pack8(l8);
        *(uint4*)(v2thi + obase + k) = pack8(h28);
        *(uint4*)(v2tlo + obase + k) = pack8(l28);
    }
}

// ---------------------------------------------------------------------------
// Cooperative 64x64 bf16 tile stage: global (stride gstride) -> LDS (stride 72)
// ---------------------------------------------------------------------------
__device__ inline void stage64(const ushort_t* __restrict__ g, long rowBase,
                               int gstride, int col0, ushort_t* l, int tid)
{
    int r  = tid >> 2;            // 0..63
    int cs = (tid & 3) << 4;      // 0,16,32,48
    const ushort_t* gp = g + (rowBase + r) * (long)gstride + col0 + cs;
    uint4 a  = *(const uint4*)gp;
    uint4 bb = *(const uint4*)(gp + 8);
    ushort_t* lp = l + r * 72 + cs;
    *(uint4*)lp       = a;
    *(uint4*)(lp + 8) = bb;
}

// ---------------------------------------------------------------------------
// Flash MFMA kernel.
// Block = 4 waves, 64 q-rows (wave w owns rows [qb*64 + 16w, +16)).
// K-tiles of 64 keys; QK in 64-channel chunks, 3 MFMAs (hi*hi, lo*hi, hi*lo).
// Softmax online in C/D layout (row = quad*4+reg, col = lane&15).
// P -> LDS (bf16) -> A-layout for PV; V/V2 staged from pre-transposed arrays.
// ---------------------------------------------------------------------------
template<int Cc, int C, int N, bool QREG>
__global__ void __launch_bounds__(256, 1) flash_mfma(
    const ushort_t* __restrict__ Qhi, const ushort_t* __restrict__ Qlo,
    const ushort_t* __restrict__ Khi, const ushort_t* __restrict__ Klo,
    const ushort_t* __restrict__ Vthi, const ushort_t* __restrict__ Vtlo,
    const ushort_t* __restrict__ V2thi, const ushort_t* __restrict__ V2tlo,
    const float* __restrict__ CTp, const float* __restrict__ CSp,
    const float* __restrict__ cmean, const float* __restrict__ crstd,
    float* __restrict__ loss)
{
    constexpr int KC    = Cc / 64;
    constexpr int VC    = C / 64;
    constexpr int CTC   = C / 16;
    constexpr int TILES = N / 64;
    constexpr int NKS   = QREG ? (Cc / 32) : 1;

    __shared__ ushort_t smem[23040];          // 4*4608 stage + 4*1152 P = 46080B
    ushort_t* A0 = smem;
    ushort_t* A1 = smem + 4608;
    ushort_t* A2 = smem + 9216;
    ushort_t* A3 = smem + 13824;

    const int tid  = threadIdx.x;
    const int lane = tid & 63;
    const int w    = tid >> 6;
    const int l15  = lane & 15;
    const int quad = lane >> 4;

    const int bPB = N / 64;
    const int b   = blockIdx.x / bPB;
    const int qb  = blockIdx.x % bPB;
    const int i0  = qb * 64 + w * 16;
    ushort_t* Pw  = smem + 18432 + w * 1152;  // 16 rows x stride 72

    // Q fragments in registers (scale-2 path)
    short8 qh[NKS], ql[NKS];
    if (QREG) {
        const ushort_t* q1 = Qhi + ((long)(b * N + i0 + l15)) * Cc + quad * 8;
        const ushort_t* q2 = Qlo + ((long)(b * N + i0 + l15)) * Cc + quad * 8;
#pragma unroll
        for (int ks = 0; ks < NKS; ++ks) {
            qh[ks] = *(const short8*)(q1 + ks * 32);
            ql[ks] = *(const short8*)(q2 + ks * 32);
        }
    }

    float m_r[4], l_r[4];
    f32x4 Mac[CTC], Sac[CTC];
#pragma unroll
    for (int r = 0; r < 4; ++r) { m_r[r] = -1e30f; l_r[r] = 0.f; }
#pragma unroll
    for (int ct = 0; ct < CTC; ++ct)
#pragma unroll
        for (int r = 0; r < 4; ++r) { Mac[ct][r] = 0.f; Sac[ct][r] = 0.f; }

    for (int kt = 0; kt < TILES; ++kt) {
        const long krow = (long)b * N + kt * 64;

        f32x4 S[4];
#pragma unroll
        for (int ct = 0; ct < 4; ++ct)
#pragma unroll
            for (int r = 0; r < 4; ++r) S[ct][r] = 0.f;

        auto qk_chunk = [&](int kc) {
            __syncthreads();
            stage64(Khi, krow, Cc, kc * 64, A0, tid);
            stage64(Klo, krow, Cc, kc * 64, A1, tid);
            if (!QREG) {
                stage64(Qhi, (long)b * N + qb * 64, Cc, kc * 64, A2, tid);
                stage64(Qlo, (long)b * N + qb * 64, Cc, kc * 64, A3, tid);
            }
            __syncthreads();
#pragma unroll
            for (int ks = 0; ks < 2; ++ks) {
                short8 ah, al;
                if (QREG) {
                    ah = qh[kc * 2 + ks];
                    al = ql[kc * 2 + ks];
                } else {
                    const int qo = (w * 16 + l15) * 72 + ks * 32 + quad * 8;
                    ah = *(const short8*)(A2 + qo);
                    al = *(const short8*)(A3 + qo);
                }
#pragma unroll
                for (int ct = 0; ct < 4; ++ct) {
                    const int ko = (ct * 16 + l15) * 72 + ks * 32 + quad * 8;
                    short8 bh = *(const short8*)(A0 + ko);
                    short8 bl = *(const short8*)(A1 + ko);
                    S[ct] = MFMA16(ah, bh, S[ct]);
                    S[ct] = MFMA16(al, bh, S[ct]);
                    S[ct] = MFMA16(ah, bl, S[ct]);
                }
            }
        };
        if (QREG) {
#pragma unroll
            for (int kc = 0; kc < KC; ++kc) qk_chunk(kc);
        } else {
            for (int kc = 0; kc < KC; ++kc) qk_chunk(kc);
        }

        // ---- online softmax ----
        float mx[4];
#pragma unroll
        for (int r = 0; r < 4; ++r)
            mx[r] = fmaxf(fmaxf(S[0][r], S[1][r]), fmaxf(S[2][r], S[3][r]));
#pragma unroll
        for (int off = 1; off <= 8; off <<= 1)
#pragma unroll
            for (int r = 0; r < 4; ++r)
                mx[r] = fmaxf(mx[r], __shfl_xor(mx[r], off, 64));
        float corr[4];
#pragma unroll
        for (int r = 0; r < 4; ++r) {
            float mn = fmaxf(m_r[r], mx[r]);
            corr[r] = __expf(m_r[r] - mn);
            m_r[r]  = mn;
            l_r[r] *= corr[r];
        }
#pragma unroll
        for (int ct = 0; ct < CTC; ++ct)
#pragma unroll
            for (int r = 0; r < 4; ++r) { Mac[ct][r] *= corr[r]; Sac[ct][r] *= corr[r]; }

        float ps[4] = {0.f, 0.f, 0.f, 0.f};
#pragma unroll
        for (int ct = 0; ct < 4; ++ct)
#pragma unroll
            for (int r = 0; r < 4; ++r) {
                float p = __expf(S[ct][r] - m_r[r]);
                ps[r] += p;
                Pw[(quad * 4 + r) * 72 + ct * 16 + l15] = bf16_bits(p);
            }
#pragma unroll
        for (int off = 1; off <= 8; off <<= 1)
#pragma unroll
            for (int r = 0; r < 4; ++r) ps[r] += __shfl_xor(ps[r], off, 64);
#pragma unroll
        for (int r = 0; r < 4; ++r) l_r[r] += ps[r];

        // ---- PV / PV^2 ----
#pragma unroll
        for (int vc = 0; vc < VC; ++vc) {
            __syncthreads();
            const long vrow = (long)b * C + vc * 64;   // rows = v-channels
            stage64(Vthi,  vrow, N, kt * 64, A0, tid);
            stage64(Vtlo,  vrow, N, kt * 64, A1, tid);
            stage64(V2thi, vrow, N, kt * 64, A2, tid);
            stage64(V2tlo, vrow, N, kt * 64, A3, tid);
            __syncthreads();
#pragma unroll
            for (int ks = 0; ks < 2; ++ks) {
                short8 pf = *(const short8*)(Pw + l15 * 72 + ks * 32 + quad * 8);
#pragma unroll
                for (int ct = 0; ct < 4; ++ct) {
                    const int vo = (ct * 16 + l15) * 72 + ks * 32 + quad * 8;
                    short8 vh = *(const short8*)(A0 + vo);
                    short8 vl = *(const short8*)(A1 + vo);
                    short8 uh = *(const short8*)(A2 + vo);
                    short8 ul = *(const short8*)(A3 + vo);
                    const int ci = vc * 4 + ct;
                    Mac[ci] = MFMA16(pf, vh, Mac[ci]);
                    Mac[ci] = MFMA16(pf, vl, Mac[ci]);
                    Sac[ci] = MFMA16(pf, uh, Sac[ci]);
                    Sac[ci] = MFMA16(pf, ul, Sac[ci]);
                }
            }
        }
    }

    // ---- fused epilogue: M, S, norm_content, MSE partial ----
    float invl[4];
#pragma unroll
    for (int r = 0; r < 4; ++r) invl[r] = 1.f / l_r[r];
    float acc = 0.f;
    const long cbase = (long)b * C;
#pragma unroll
    for (int ct = 0; ct < CTC; ++ct) {
        const int ch = ct * 16 + l15;
        const float cm = cmean[cbase + ch];
        const float cr = crstd[cbase + ch];
#pragma unroll
        for (int r = 0; r < 4; ++r) {
            const long row = (long)b * N + i0 + quad * 4 + r;
            float Mv = Mac[ct][r] * invl[r];
            float S2 = Sac[ct][r] * invl[r] - Mv * Mv;
            float Sv = sqrtf(fmaxf(S2, EPS_VAR));
            float nc = (CTp[row * C + ch] - cm) * cr;
            float d  = CSp[row * C + ch] - (Sv * nc + Mv);
            acc = fmaf(d, d, acc);
        }
    }
#pragma unroll
    for (int off = 1; off <= 32; off <<= 1) acc += __shfl_xor(acc, off, 64);
    if (lane == 0) atomicAdd(loss, acc);
}

// ---------------------------------------------------------------------------
// Fallback scalar flash kernel (round-1, used only if ws_size too small)
// ---------------------------------------------------------------------------
template<int CCL, int CL, int NQ>
__global__ void __launch_bounds__(256) flash_aat(
    const float* __restrict__ Q, const float* __restrict__ K, const float* __restrict__ V,
    const float* __restrict__ CT, const float* __restrict__ CS,
    const float* __restrict__ qmean, const float* __restrict__ qrstd,
    const float* __restrict__ kmean, const float* __restrict__ krstd,
    const float* __restrict__ cmean, const float* __restrict__ crstd,
    float* __restrict__ loss, int N)
{
    constexpr int CC   = CCL * 64;
    constexpr int C    = CL * 64;
    constexpr int ROWS = 4 * NQ;
    const int lane = threadIdx.x & 63;
    const int wave = threadIdx.x >> 6;
    const int rowBlocks = N / ROWS;
    const int b  = blockIdx.x / rowBlocks;
    const int rb = blockIdx.x % rowBlocks;
    const int i0 = rb * ROWS + wave * NQ;

    float kmu[CCL], krs[CCL];
#pragma unroll
    for (int t = 0; t < CCL; ++t) {
        int ch = lane + 64 * t;
        kmu[t] = kmean[b * CC + ch];
        krs[t] = krstd[b * CC + ch];
    }
    float q[NQ][CCL];
#pragma unroll
    for (int qi = 0; qi < NQ; ++qi) {
        long base = (long)(b * N + i0 + qi) * CC;
#pragma unroll
        for (int t = 0; t < CCL; ++t) {
            int ch = lane + 64 * t;
            q[qi][t] = (Q[base + ch] - qmean[b * CC + ch]) * qrstd[b * CC + ch];
        }
    }
    float mval[NQ], lsum[NQ];
    float Macc[NQ][CL], Sacc[NQ][CL];
#pragma unroll
    for (int qi = 0; qi < NQ; ++qi) {
        mval[qi] = -1e30f; lsum[qi] = 0.f;
#pragma unroll
        for (int t = 0; t < CL; ++t) { Macc[qi][t] = 0.f; Sacc[qi][t] = 0.f; }
    }
    for (int j = 0; j < N; ++j) {
        long kb = (long)(b * N + j) * CC;
        float dot[NQ];
#pragma unroll
        for (int qi = 0; qi < NQ; ++qi) dot[qi] = 0.f;
#pragma unroll
        for (int t = 0; t < CCL; ++t) {
            float kv = (K[kb + lane + 64 * t] - kmu[t]) * krs[t];
#pragma unroll
            for (int qi = 0; qi < NQ; ++qi) dot[qi] = fmaf(q[qi][t], kv, dot[qi]);
        }
#pragma unroll
        for (int off = 32; off > 0; off >>= 1)
#pragma unroll
            for (int qi = 0; qi < NQ; ++qi) dot[qi] += __shfl_xor(dot[qi], off, 64);
        long vb = (long)(b * N + j) * C;
        float vv[CL];
#pragma unroll
        for (int t = 0; t < CL; ++t) vv[t] = V[vb + lane + 64 * t];
#pragma unroll
        for (int qi = 0; qi < NQ; ++qi) {
            float s = dot[qi];
            float p;
            if (s > mval[qi]) {
                float cr2 = __expf(mval[qi] - s);
                lsum[qi] *= cr2;
#pragma unroll
                for (int t = 0; t < CL; ++t) { Macc[qi][t] *= cr2; Sacc[qi][t] *= cr2; }
                mval[qi] = s; p = 1.f;
            } else p = __expf(s - mval[qi]);
            lsum[qi] += p;
#pragma unroll
            for (int t = 0; t < CL; ++t) {
                float pv = p * vv[t];
                Macc[qi][t] += pv;
                Sacc[qi][t] = fmaf(pv, vv[t], Sacc[qi][t]);
            }
        }
    }
    float acc = 0.f;
#pragma unroll
    for (int qi = 0; qi < NQ; ++qi) {
        float inv_l = 1.f / lsum[qi];
        long base = (long)(b * N + i0 + qi) * C;
#pragma unroll
        for (int t = 0; t < CL; ++t) {
            int ch = lane + 64 * t;
            float M  = Macc[qi][t] * inv_l;
            float S2 = Sacc[qi][t] * inv_l - M * M;
            float S  = sqrtf(fmaxf(S2, EPS_VAR));
            float nc = (CT[base + ch] - cmean[b * C + ch]) * crstd[b * C + ch];
            float d  = CS[base + ch] - (S * nc + M);
            acc = fmaf(d, d, acc);
        }
    }
#pragma unroll
    for (int off = 32; off > 0; off >>= 1) acc += __shfl_xor(acc, off, 64);
    if (lane == 0) atomicAdd(loss, acc);
}

__global__ void combine_loss(const float* __restrict__ lp, float* __restrict__ out,
                             float s0, float s1, float s2)
{
    out[0] = lp[0] * s0 + lp[1] * s1 + lp[2] * s2;
}

// ---------------------------------------------------------------------------
extern "C" void kernel_launch(void* const* d_in, const int* in_sizes, int n_in,
                              void* d_out, int out_size, void* d_ws, size_t ws_size,
                              hipStream_t stream)
{
    const float* cs2 = (const float*)d_in[0];
    const float* c2  = (const float*)d_in[1];
    const float* s2v = (const float*)d_in[2];
    const float* cc2 = (const float*)d_in[3];
    const float* sc2 = (const float*)d_in[4];
    const float* cs3 = (const float*)d_in[5];
    const float* c3  = (const float*)d_in[6];
    const float* s3v = (const float*)d_in[7];
    const float* cc3 = (const float*)d_in[8];
    const float* sc3 = (const float*)d_in[9];
    const float* cs4 = (const float*)d_in[10];
    const float* c4  = (const float*)d_in[11];
    const float* s4v = (const float*)d_in[12];
    const float* cc4 = (const float*)d_in[13];
    const float* sc4 = (const float*)d_in[14];

    const int B = 4;
    float* ws = (float*)d_ws;
    size_t fo = 0;
    auto allocF = [&](size_t n) { float* p = ws + fo; fo += n; return p; };

    float* lossp = allocF(4);
    float* c2m = allocF(B * 256);  float* c2r = allocF(B * 256);
    float* q2m = allocF(B * 448);  float* q2r = allocF(B * 448);
    float* k2m = allocF(B * 448);  float* k2r = allocF(B * 448);
    float* c3m = allocF(B * 512);  float* c3r = allocF(B * 512);
    float* q3m = allocF(B * 960);  float* q3r = allocF(B * 960);
    float* k3m = allocF(B * 960);  float* k3r = allocF(B * 960);
    float* c4m = allocF(B * 512);  float* c4r = allocF(B * 512);
    float* q4m = allocF(B * 1472); float* q4r = allocF(B * 1472);
    float* k4m = allocF(B * 1472); float* k4r = allocF(B * 1472);
    size_t zeroBytes = fo * sizeof(float);

    // bf16 arena (16B aligned)
    size_t uo = ((fo * 4 + 15) & ~(size_t)15) / 2;
    ushort_t* uws = (ushort_t*)d_ws;
    auto allocU = [&](size_t n) { ushort_t* p = uws + uo; uo += (n + 7) & ~(size_t)7; return p; };

    ushort_t *q2hi = allocU((size_t)B*4096*448), *q2lo = allocU((size_t)B*4096*448);
    ushort_t *k2hi = allocU((size_t)B*4096*448), *k2lo = allocU((size_t)B*4096*448);
    ushort_t *v2hi = allocU((size_t)B*4096*256), *v2lo = allocU((size_t)B*4096*256);
    ushort_t *w2hi = allocU((size_t)B*4096*256), *w2lo = allocU((size_t)B*4096*256);
    ushort_t *q3hi = allocU((size_t)B*1024*960), *q3lo = allocU((size_t)B*1024*960);
    ushort_t *k3hi = allocU((size_t)B*1024*960), *k3lo = allocU((size_t)B*1024*960);
    ushort_t *v3hi = allocU((size_t)B*1024*512), *v3lo = allocU((size_t)B*1024*512);
    ushort_t *w3hi = allocU((size_t)B*1024*512), *w3lo = allocU((size_t)B*1024*512);
    ushort_t *q4hi = allocU((size_t)B*256*1472), *q4lo = allocU((size_t)B*256*1472);
    ushort_t *k4hi = allocU((size_t)B*256*1472), *k4lo = allocU((size_t)B*256*1472);
    ushort_t *v4hi = allocU((size_t)B*256*512),  *v4lo = allocU((size_t)B*256*512);
    ushort_t *w4hi = allocU((size_t)B*256*512),  *w4lo = allocU((size_t)B*256*512);
    size_t need = uo * 2;
    const bool fast = (ws_size >= need);

    hipMemsetAsync(d_ws, 0, zeroBytes, stream);

    auto stats = [&](const float* x, float* sm, float* sq, int N, int Cn) {
        int chG  = (Cn + 255) / 256;
        int nPer = 256;
        int nG   = (N + nPer - 1) / nPer;
        hipLaunchKernelGGL(stat_partial, dim3(B * chG * nG), dim3(256), 0, stream,
                           x, sm, sq, N, Cn, chG, nG, nPer);
        int total = B * Cn;
        hipLaunchKernelGGL(stat_finalize, dim3((total + 255) / 256), dim3(256), 0, stream,
                           sm, sq, total, 1.0f / (float)N);
    };

    stats(c2,  c2m, c2r, 4096, 256);
    stats(cc2, q2m, q2r, 4096, 448);
    stats(sc2, k2m, k2r, 4096, 448);
    stats(c3,  c3m, c3r, 1024, 512);
    stats(cc3, q3m, q3r, 1024, 960);
    stats(sc3, k3m, k3r, 1024, 960);
    stats(c4,  c4m, c4r, 256, 512);
    stats(cc4, q4m, q4r, 256, 1472);
    stats(sc4, k4m, k4r, 256, 1472);

    if (fast) {
        // normalize+split Q/K
        hipLaunchKernelGGL(norm_split, dim3(B*4096), dim3(256), 0, stream, cc2, q2m, q2r, q2hi, q2lo, 4096, 448);
        hipLaunchKernelGGL(norm_split, dim3(B*4096), dim3(256), 0, stream, sc2, k2m, k2r, k2hi, k2lo, 4096, 448);
        hipLaunchKernelGGL(norm_split, dim3(B*1024), dim3(256), 0, stream, cc3, q3m, q3r, q3hi, q3lo, 1024, 960);
        hipLaunchKernelGGL(norm_split, dim3(B*1024), dim3(256), 0, stream, sc3, k3m, k3r, k3hi, k3lo, 1024, 960);
        hipLaunchKernelGGL(norm_split, dim3(B*256),  dim3(256), 0, stream, cc4, q4m, q4r, q4hi, q4lo, 256, 1472);
        hipLaunchKernelGGL(norm_split, dim3(B*256),  dim3(256), 0, stream, sc4, k4m, k4r, k4hi, k4lo, 256, 1472);
        // V transpose + square split
        hipLaunchKernelGGL((vsplit_t<512>), dim3(B*(256/64)*(4096/512)), dim3(256), 0, stream,
                           s2v, v2hi, v2lo, w2hi, w2lo, 4096, 256);
        hipLaunchKernelGGL((vsplit_t<512>), dim3(B*(512/64)*(1024/512)), dim3(256), 0, stream,
                           s3v, v3hi, v3lo, w3hi, w3lo, 1024, 512);
        hipLaunchKernelGGL((vsplit_t<256>), dim3(B*(512/64)*(256/256)), dim3(256), 0, stream,
                           s4v, v4hi, v4lo, w4hi, w4lo, 256, 512);
        // flash MFMA
        hipLaunchKernelGGL((flash_mfma<448, 256, 4096, true>),  dim3(B*4096/64), dim3(256), 0, stream,
                           q2hi, q2lo, k2hi, k2lo, v2hi, v2lo, w2hi, w2lo,
                           c2, cs2, c2m, c2r, &lossp[0]);
        hipLaunchKernelGGL((flash_mfma<960, 512, 1024, false>), dim3(B*1024/64), dim3(256), 0, stream,
                           q3hi, q3lo, k3hi, k3lo, v3hi, v3lo, w3hi, w3lo,
                           c3, cs3, c3m, c3r, &lossp[1]);
        hipLaunchKernelGGL((flash_mfma<1472, 512, 256, false>), dim3(B*256/64), dim3(256), 0, stream,
                           q4hi, q4lo, k4hi, k4lo, v4hi, v4lo, w4hi, w4lo,
                           c4, cs4, c4m, c4r, &lossp[2]);
    } else {
        hipLaunchKernelGGL((flash_aat<7, 4, 4>), dim3(B * 4096 / 16), dim3(256), 0, stream,
                           cc2, sc2, s2v, c2, cs2, q2m, q2r, k2m, k2r, c2m, c2r, &lossp[0], 4096);
        hipLaunchKernelGGL((flash_aat<15, 8, 2>), dim3(B * 1024 / 8), dim3(256), 0, stream,
                           cc3, sc3, s3v, c3, cs3, q3m, q3r, k3m, k3r, c3m, c3r, &lossp[1], 1024);
        hipLaunchKernelGGL((flash_aat<23, 8, 2>), dim3(B * 256 / 8), dim3(256), 0, stream,
                           cc4, sc4, s4v, c4, cs4, q4m, q4r, k4m, k4r, c4m, c4r, &lossp[2], 256);
    }

    hipLaunchKernelGGL(combine_loss, dim3(1), dim3(1), 0, stream,
                       lossp, (float*)d_out,
                       1.0f / (4.0f * 4096.0f * 256.0f),
                       1.0f / (4.0f * 1024.0f * 512.0f),
                       1.0f / (4.0f * 256.0f * 512.0f));
}

// Round 3
// 2233.058 us; speedup vs baseline: 4.0422x; 1.5904x over previous
//
#include <hip/hip_runtime.h>
#include <math.h>

#define EPS_NORM 1e-5f
#define EPS_VAR  1e-9f

typedef unsigned short ushort_t;
typedef __attribute__((ext_vector_type(8))) short short8;
typedef __attribute__((ext_vector_type(4))) float f32x4;

#define MFMA16(a, b, c) __builtin_amdgcn_mfma_f32_16x16x32_bf16((a), (b), (c), 0, 0, 0)

// ---------------------------------------------------------------------------
// bf16 helpers (RNE), header-independent
// ---------------------------------------------------------------------------
__device__ inline ushort_t bf16_bits(float x) {
    union { float f; unsigned u; } v; v.f = x;
    unsigned r = v.u + 0x7fffu + ((v.u >> 16) & 1u);
    return (ushort_t)(r >> 16);
}
__device__ inline float bf16_back(ushort_t b) {
    union { unsigned u; float f; } v; v.u = ((unsigned)b) << 16;
    return v.f;
}
__device__ inline uint4 pack8(const ushort_t* s) {
    uint4 r;
    r.x = (unsigned)s[0] | ((unsigned)s[1] << 16);
    r.y = (unsigned)s[2] | ((unsigned)s[3] << 16);
    r.z = (unsigned)s[4] | ((unsigned)s[5] << 16);
    r.w = (unsigned)s[6] | ((unsigned)s[7] << 16);
    return r;
}

// ---------------------------------------------------------------------------
// Stage 1: per-(batch, channel) sum / sumsq over spatial axis (split-N atomic)
// ---------------------------------------------------------------------------
__global__ void __launch_bounds__(256) stat_partial(
    const float* __restrict__ x, float* __restrict__ sum, float* __restrict__ sumsq,
    int N, int Cn, int chG, int nG, int nPer)
{
    int bx = blockIdx.x;
    int b  = bx / (chG * nG);
    int r  = bx % (chG * nG);
    int cg = r / nG;
    int ng = r % nG;
    int ch = cg * 256 + threadIdx.x;
    if (ch >= Cn) return;
    int n0 = ng * nPer;
    int n1 = min(n0 + nPer, N);
    const float* p = x + (long)(b * N) * Cn + ch;
    float s = 0.f, ss = 0.f;
    for (int n = n0; n < n1; ++n) {
        float v = p[(long)n * Cn];
        s += v;
        ss = fmaf(v, v, ss);
    }
    atomicAdd(&sum[b * Cn + ch], s);
    atomicAdd(&sumsq[b * Cn + ch], ss);
}

__global__ void __launch_bounds__(256) stat_finalize(
    float* __restrict__ sum, float* __restrict__ sumsq, int total, float invN)
{
    int i = blockIdx.x * blockDim.x + threadIdx.x;
    if (i >= total) return;
    float m = sum[i] * invN;
    float v = sumsq[i] * invN - m * m;
    sum[i]   = m;
    sumsq[i] = rsqrtf(v + EPS_NORM);
}

// ---------------------------------------------------------------------------
// Prepass: normalize X (B,N,Cn) and split to bf16 hi/lo (same layout)
// ---------------------------------------------------------------------------
__global__ void __launch_bounds__(256) norm_split(
    const float* __restrict__ x, const float* __restrict__ mean,
    const float* __restrict__ rstd,
    ushort_t* __restrict__ hi, ushort_t* __restrict__ lo, int N, int Cn)
{
    int bn = blockIdx.x;          // b*N + n
    int b  = bn / N;
    long base = (long)bn * Cn;
    for (int ch = threadIdx.x; ch < Cn; ch += 256) {
        float v = (x[base + ch] - mean[b * Cn + ch]) * rstd[b * Cn + ch];
        ushort_t h = bf16_bits(v);
        hi[base + ch] = h;
        lo[base + ch] = bf16_bits(v - bf16_back(h));
    }
}

// ---------------------------------------------------------------------------
// Prepass: V (B,N,C) -> transposed (B,C,N): bf16 hi of v; hi+lo of v^2.
// (V-lo dropped: M only needs 2^-9 relative; S2 needs absolute precision.)
// ---------------------------------------------------------------------------
template<int KSEG>
__global__ void __launch_bounds__(256) vsplit_t(
    const float* __restrict__ v,
    ushort_t* __restrict__ vthi, ushort_t* __restrict__ v2thi,
    ushort_t* __restrict__ v2tlo, int N, int C)
{
    int cPB = C / 64, nSeg = N / KSEG;
    int bid = blockIdx.x;
    int b   = bid / (cPB * nSeg);
    int rem = bid % (cPB * nSeg);
    int cb  = rem / nSeg;
    int ns  = rem % nSeg;
    int ch  = cb * 64 + (threadIdx.x & 63);
    const int KL = KSEG / 4;
    int k0  = ns * KSEG + (threadIdx.x >> 6) * KL;
    long obase = ((long)b * C + ch) * N;
    for (int k = k0; k < k0 + KL; k += 8) {
        ushort_t h8[8], h28[8], l28[8];
#pragma unroll
        for (int i = 0; i < 8; ++i) {
            float x  = v[((long)b * N + k + i) * C + ch];
            h8[i] = bf16_bits(x);
            float x2 = x * x;
            ushort_t h2 = bf16_bits(x2);
            h28[i] = h2;
            l28[i] = bf16_bits(x2 - bf16_back(h2));
        }
        *(uint4*)(vthi  + obase + k) = pack8(h8);
        *(uint4*)(v2thi + obase + k) = pack8(h28);
        *(uint4*)(v2tlo + obase + k) = pack8(l28);
    }
}

// ---------------------------------------------------------------------------
// Cooperative tile stagers: global (stride gstride) -> LDS (stride 72)
// ---------------------------------------------------------------------------
__device__ inline void stage64(const ushort_t* __restrict__ g, long rowBase,
                               int gstride, int col0, ushort_t* l, int tid)
{
    int r  = tid >> 2;            // 0..63
    int cs = (tid & 3) << 4;      // 0,16,32,48
    const ushort_t* gp = g + (rowBase + r) * (long)gstride + col0 + cs;
    uint4 a  = *(const uint4*)gp;
    uint4 bb = *(const uint4*)(gp + 8);
    ushort_t* lp = l + r * 72 + cs;
    *(uint4*)lp       = a;
    *(uint4*)(lp + 8) = bb;
}
__device__ inline void stage32(const ushort_t* __restrict__ g, long rowBase,
                               int gstride, int col0, ushort_t* l, int tid)
{
    int r  = tid >> 3;            // 0..31
    int cs = (tid & 7) << 3;      // 0,8,..,56 (shorts)
    const ushort_t* gp = g + (rowBase + r) * (long)gstride + col0 + cs;
    uint4 a = *(const uint4*)gp;
    *(uint4*)(l + r * 72 + cs) = a;
}

// ---------------------------------------------------------------------------
// Flash MFMA kernel with key-split and optional C-split.
// CSPLIT=1: 4 waves = 4 q-stripes (64 rows/block), full C per wave.
// CSPLIT=2: wave pairs share a q-stripe (32 rows/block), each half of C.
// Keys [sp*NKT*64, ...) per block; partial (m,l,SumPV,SumPV2) -> workspace.
// ---------------------------------------------------------------------------
template<int Cc, int C, int N, int CSPLIT, bool QREG, int SPLIT>
__global__ void __launch_bounds__(256, 2) flash_mfma(
    const ushort_t* __restrict__ Qhi, const ushort_t* __restrict__ Qlo,
    const ushort_t* __restrict__ Khi, const ushort_t* __restrict__ Klo,
    const ushort_t* __restrict__ Vthi, const ushort_t* __restrict__ V2thi,
    const ushort_t* __restrict__ V2tlo,
    float* __restrict__ Pmo, float* __restrict__ Plo,
    float* __restrict__ PMo, float* __restrict__ PSo)
{
    constexpr int KC      = Cc / 64;
    constexpr int VC      = C / 64;
    constexpr int VCW     = VC / CSPLIT;
    constexpr int CTCW    = 4 * VCW;
    constexpr int STRIPES = 4 / CSPLIT;
    constexpr int BROWS   = 16 * STRIPES;
    constexpr int QB      = N / BROWS;
    constexpr int NKT     = (N / 64) / SPLIT;
    constexpr int NKS     = QREG ? (Cc / 32) : 1;

    __shared__ ushort_t smem[32256];   // 6 stage slots*4608 + 4 P slots*1152
    const int tid  = threadIdx.x;
    const int lane = tid & 63;
    const int w    = tid >> 6;
    const int l15  = lane & 15;
    const int quad = lane >> 4;

    const int bq = blockIdx.x / SPLIT;
    const int sp = blockIdx.x % SPLIT;
    const int b  = bq / QB;
    const int qb = bq % QB;
    const int ls  = w / CSPLIT;       // stripe within block
    const int ch2 = w % CSPLIT;       // channel half
    const int i0 = qb * BROWS + ls * 16;
    const long po = (long)(b * (N / 16) + qb * STRIPES + ls) * SPLIT + sp;
    ushort_t* Pw = smem + 27648 + w * 1152;

    ushort_t* A0 = smem;
    ushort_t* A1 = smem + 4608;
    ushort_t* A2 = smem + 9216;
    ushort_t* A3 = smem + 13824;

    short8 qh[NKS], ql[NKS];
    if (QREG) {
        const ushort_t* q1 = Qhi + ((long)(b * N + i0 + l15)) * Cc + quad * 8;
        const ushort_t* q2 = Qlo + ((long)(b * N + i0 + l15)) * Cc + quad * 8;
#pragma unroll
        for (int ks = 0; ks < NKS; ++ks) {
            qh[ks] = *(const short8*)(q1 + ks * 32);
            ql[ks] = *(const short8*)(q2 + ks * 32);
        }
    }

    float m_r[4], l_r[4];
    f32x4 Mac[CTCW], Sac[CTCW];
#pragma unroll
    for (int r = 0; r < 4; ++r) { m_r[r] = -1e30f; l_r[r] = 0.f; }
#pragma unroll
    for (int ct = 0; ct < CTCW; ++ct)
#pragma unroll
        for (int r = 0; r < 4; ++r) { Mac[ct][r] = 0.f; Sac[ct][r] = 0.f; }

    for (int kt = sp * NKT; kt < sp * NKT + NKT; ++kt) {
        const long krow = (long)b * N + kt * 64;

        f32x4 S[4];
#pragma unroll
        for (int ct = 0; ct < 4; ++ct)
#pragma unroll
            for (int r = 0; r < 4; ++r) S[ct][r] = 0.f;

        for (int kc = 0; kc < KC; ++kc) {
            __syncthreads();
            stage64(Khi, krow, Cc, kc * 64, A0, tid);
            stage64(Klo, krow, Cc, kc * 64, A1, tid);
            if (!QREG) {
                stage32(Qhi, (long)b * N + qb * BROWS, Cc, kc * 64, A2, tid);
                stage32(Qlo, (long)b * N + qb * BROWS, Cc, kc * 64, A3, tid);
            }
            __syncthreads();
#pragma unroll
            for (int ks = 0; ks < 2; ++ks) {
                short8 ah, al;
                if (QREG) {
                    ah = qh[kc * 2 + ks];
                    al = ql[kc * 2 + ks];
                } else {
                    const int qo = (ls * 16 + l15) * 72 + ks * 32 + quad * 8;
                    ah = *(const short8*)(A2 + qo);
                    al = *(const short8*)(A3 + qo);
                }
#pragma unroll
                for (int ct = 0; ct < 4; ++ct) {
                    const int ko = (ct * 16 + l15) * 72 + ks * 32 + quad * 8;
                    short8 bh = *(const short8*)(A0 + ko);
                    short8 bl = *(const short8*)(A1 + ko);
                    S[ct] = MFMA16(ah, bh, S[ct]);
                    S[ct] = MFMA16(al, bh, S[ct]);
                    S[ct] = MFMA16(ah, bl, S[ct]);
                }
            }
        }

        // ---- online softmax (C/D layout: row=quad*4+r, col=l15) ----
        float mx[4];
#pragma unroll
        for (int r = 0; r < 4; ++r)
            mx[r] = fmaxf(fmaxf(S[0][r], S[1][r]), fmaxf(S[2][r], S[3][r]));
#pragma unroll
        for (int off = 1; off <= 8; off <<= 1)
#pragma unroll
            for (int r = 0; r < 4; ++r)
                mx[r] = fmaxf(mx[r], __shfl_xor(mx[r], off, 64));
        float corr[4];
#pragma unroll
        for (int r = 0; r < 4; ++r) {
            float mn = fmaxf(m_r[r], mx[r]);
            corr[r] = __expf(m_r[r] - mn);
            m_r[r]  = mn;
            l_r[r] *= corr[r];
        }
#pragma unroll
        for (int ct = 0; ct < CTCW; ++ct)
#pragma unroll
            for (int r = 0; r < 4; ++r) { Mac[ct][r] *= corr[r]; Sac[ct][r] *= corr[r]; }

        float ps[4] = {0.f, 0.f, 0.f, 0.f};
#pragma unroll
        for (int ct = 0; ct < 4; ++ct)
#pragma unroll
            for (int r = 0; r < 4; ++r) {
                float p = __expf(S[ct][r] - m_r[r]);
                ps[r] += p;
                Pw[(quad * 4 + r) * 72 + ct * 16 + l15] = bf16_bits(p);
            }
#pragma unroll
        for (int off = 1; off <= 8; off <<= 1)
#pragma unroll
            for (int r = 0; r < 4; ++r) ps[r] += __shfl_xor(ps[r], off, 64);
#pragma unroll
        for (int r = 0; r < 4; ++r) l_r[r] += ps[r];

        // ---- PV / PV^2 ----
#pragma unroll
        for (int vcl = 0; vcl < VCW; ++vcl) {
            __syncthreads();
#pragma unroll
            for (int h = 0; h < CSPLIT; ++h) {
                const int chunk = h * VCW + vcl;
                const long vrow = (long)b * C + chunk * 64;
                stage64(Vthi,  vrow, N, kt * 64, smem + (3 * h + 0) * 4608, tid);
                stage64(V2thi, vrow, N, kt * 64, smem + (3 * h + 1) * 4608, tid);
                stage64(V2tlo, vrow, N, kt * 64, smem + (3 * h + 2) * 4608, tid);
            }
            __syncthreads();
            const ushort_t* Bv = smem + (3 * ch2) * 4608;
#pragma unroll
            for (int ks = 0; ks < 2; ++ks) {
                short8 pf = *(const short8*)(Pw + l15 * 72 + ks * 32 + quad * 8);
#pragma unroll
                for (int ct = 0; ct < 4; ++ct) {
                    const int vo = (ct * 16 + l15) * 72 + ks * 32 + quad * 8;
                    short8 vh = *(const short8*)(Bv + vo);
                    short8 uh = *(const short8*)(Bv + 4608 + vo);
                    short8 ul = *(const short8*)(Bv + 9216 + vo);
                    const int ci = vcl * 4 + ct;
                    Mac[ci] = MFMA16(pf, vh, Mac[ci]);
                    Sac[ci] = MFMA16(pf, uh, Sac[ci]);
                    Sac[ci] = MFMA16(pf, ul, Sac[ci]);
                }
            }
        }
    }

    // ---- dump partial state ----
    if (ch2 == 0 && l15 == 0) {
#pragma unroll
        for (int r = 0; r < 4; ++r) {
            Pmo[po * 16 + quad * 4 + r] = m_r[r];
            Plo[po * 16 + quad * 4 + r] = l_r[r];
        }
    }
    const int chb = ch2 * (C / CSPLIT);
#pragma unroll
    for (int ct = 0; ct < CTCW; ++ct)
#pragma unroll
        for (int r = 0; r < 4; ++r) {
            long idx = (po * 16 + quad * 4 + r) * C + chb + ct * 16 + l15;
            PMo[idx] = Mac[ct][r];
            PSo[idx] = Sac[ct][r];
        }
}

// ---------------------------------------------------------------------------
// Combine: merge SPLIT flash partials per 16-row stripe, fused epilogue + MSE.
// ---------------------------------------------------------------------------
template<int C, int SPLIT>
__global__ void __launch_bounds__(256) combine_aat(
    const float* __restrict__ Pm, const float* __restrict__ Pl,
    const float* __restrict__ PM, const float* __restrict__ PS,
    const float* __restrict__ CT, const float* __restrict__ CS,
    const float* __restrict__ cmean, const float* __restrict__ crstd,
    float* __restrict__ loss, int N)
{
    __shared__ float wS[SPLIT][16];
    __shared__ float invL[16];
    __shared__ float red[4];
    const int pi = blockIdx.x;
    const int nb = N / 16;
    const int b  = pi / nb;
    const long g0 = (long)b * N + (long)(pi % nb) * 16;
    const int tid = threadIdx.x;

    if (tid < 16) {
        float m = -1e30f;
#pragma unroll
        for (int s = 0; s < SPLIT; ++s)
            m = fmaxf(m, Pm[((long)pi * SPLIT + s) * 16 + tid]);
        float L = 0.f;
#pragma unroll
        for (int s = 0; s < SPLIT; ++s) {
            float e = __expf(Pm[((long)pi * SPLIT + s) * 16 + tid] - m);
            wS[s][tid] = e;
            L = fmaf(e, Pl[((long)pi * SPLIT + s) * 16 + tid], L);
        }
        invL[tid] = 1.f / L;
    }
    __syncthreads();

    float acc = 0.f;
    for (int e = tid; e < 16 * C; e += 256) {
        const int r  = e / C;
        const int ch = e % C;
        float Ms = 0.f, Ss = 0.f;
#pragma unroll
        for (int s = 0; s < SPLIT; ++s) {
            const long q = (((long)pi * SPLIT + s) * 16 + r) * C + ch;
            Ms = fmaf(wS[s][r], PM[q], Ms);
            Ss = fmaf(wS[s][r], PS[q], Ss);
        }
        const float M  = Ms * invL[r];
        const float S2 = Ss * invL[r] - M * M;
        const float S  = sqrtf(fmaxf(S2, EPS_VAR));
        const float nc = (CT[(g0 + r) * C + ch] - cmean[b * C + ch]) * crstd[b * C + ch];
        const float d  = CS[(g0 + r) * C + ch] - (S * nc + M);
        acc = fmaf(d, d, acc);
    }
#pragma unroll
    for (int off = 1; off <= 32; off <<= 1) acc += __shfl_xor(acc, off, 64);
    if ((tid & 63) == 0) red[tid >> 6] = acc;
    __syncthreads();
    if (tid == 0) atomicAdd(loss, red[0] + red[1] + red[2] + red[3]);
}

// ---------------------------------------------------------------------------
// Fallback scalar flash kernel (only if ws_size too small)
// ---------------------------------------------------------------------------
template<int CCL, int CL, int NQ>
__global__ void __launch_bounds__(256) flash_aat(
    const float* __restrict__ Q, const float* __restrict__ K, const float* __restrict__ V,
    const float* __restrict__ CT, const float* __restrict__ CS,
    const float* __restrict__ qmean, const float* __restrict__ qrstd,
    const float* __restrict__ kmean, const float* __restrict__ krstd,
    const float* __restrict__ cmean, const float* __restrict__ crstd,
    float* __restrict__ loss, int N)
{
    constexpr int CC   = CCL * 64;
    constexpr int C    = CL * 64;
    constexpr int ROWS = 4 * NQ;
    const int lane = threadIdx.x & 63;
    const int wave = threadIdx.x >> 6;
    const int rowBlocks = N / ROWS;
    const int b  = blockIdx.x / rowBlocks;
    const int rb = blockIdx.x % rowBlocks;
    const int i0 = rb * ROWS + wave * NQ;

    float kmu[CCL], krs[CCL];
#pragma unroll
    for (int t = 0; t < CCL; ++t) {
        int ch = lane + 64 * t;
        kmu[t] = kmean[b * CC + ch];
        krs[t] = krstd[b * CC + ch];
    }
    float q[NQ][CCL];
#pragma unroll
    for (int qi = 0; qi < NQ; ++qi) {
        long base = (long)(b * N + i0 + qi) * CC;
#pragma unroll
        for (int t = 0; t < CCL; ++t) {
            int ch = lane + 64 * t;
            q[qi][t] = (Q[base + ch] - qmean[b * CC + ch]) * qrstd[b * CC + ch];
        }
    }
    float mval[NQ], lsum[NQ];
    float Macc[NQ][CL], Sacc[NQ][CL];
#pragma unroll
    for (int qi = 0; qi < NQ; ++qi) {
        mval[qi] = -1e30f; lsum[qi] = 0.f;
#pragma unroll
        for (int t = 0; t < CL; ++t) { Macc[qi][t] = 0.f; Sacc[qi][t] = 0.f; }
    }
    for (int j = 0; j < N; ++j) {
        long kb = (long)(b * N + j) * CC;
        float dot[NQ];
#pragma unroll
        for (int qi = 0; qi < NQ; ++qi) dot[qi] = 0.f;
#pragma unroll
        for (int t = 0; t < CCL; ++t) {
            float kv = (K[kb + lane + 64 * t] - kmu[t]) * krs[t];
#pragma unroll
            for (int qi = 0; qi < NQ; ++qi) dot[qi] = fmaf(q[qi][t], kv, dot[qi]);
        }
#pragma unroll
        for (int off = 32; off > 0; off >>= 1)
#pragma unroll
            for (int qi = 0; qi < NQ; ++qi) dot[qi] += __shfl_xor(dot[qi], off, 64);
        long vb = (long)(b * N + j) * C;
        float vv[CL];
#pragma unroll
        for (int t = 0; t < CL; ++t) vv[t] = V[vb + lane + 64 * t];
#pragma unroll
        for (int qi = 0; qi < NQ; ++qi) {
            float s = dot[qi];
            float p;
            if (s > mval[qi]) {
                float cr2 = __expf(mval[qi] - s);
                lsum[qi] *= cr2;
#pragma unroll
                for (int t = 0; t < CL; ++t) { Macc[qi][t] *= cr2; Sacc[qi][t] *= cr2; }
                mval[qi] = s; p = 1.f;
            } else p = __expf(s - mval[qi]);
            lsum[qi] += p;
#pragma unroll
            for (int t = 0; t < CL; ++t) {
                float pv = p * vv[t];
                Macc[qi][t] += pv;
                Sacc[qi][t] = fmaf(pv, vv[t], Sacc[qi][t]);
            }
        }
    }
    float acc = 0.f;
#pragma unroll
    for (int qi = 0; qi < NQ; ++qi) {
        float inv_l = 1.f / lsum[qi];
        long base = (long)(b * N + i0 + qi) * C;
#pragma unroll
        for (int t = 0; t < CL; ++t) {
            int ch = lane + 64 * t;
            float M  = Macc[qi][t] * inv_l;
            float S2 = Sacc[qi][t] * inv_l - M * M;
            float S  = sqrtf(fmaxf(S2, EPS_VAR));
            float nc = (CT[base + ch] - cmean[b * C + ch]) * crstd[b * C + ch];
            float d  = CS[base + ch] - (S * nc + M);
            acc = fmaf(d, d, acc);
        }
    }
#pragma unroll
    for (int off = 32; off > 0; off >>= 1) acc += __shfl_xor(acc, off, 64);
    if (lane == 0) atomicAdd(loss, acc);
}

__global__ void combine_loss(const float* __restrict__ lp, float* __restrict__ out,
                             float s0, float s1, float s2)
{
    out[0] = lp[0] * s0 + lp[1] * s1 + lp[2] * s2;
}

// ---------------------------------------------------------------------------
extern "C" void kernel_launch(void* const* d_in, const int* in_sizes, int n_in,
                              void* d_out, int out_size, void* d_ws, size_t ws_size,
                              hipStream_t stream)
{
    const float* cs2 = (const float*)d_in[0];
    const float* c2  = (const float*)d_in[1];
    const float* s2v = (const float*)d_in[2];
    const float* cc2 = (const float*)d_in[3];
    const float* sc2 = (const float*)d_in[4];
    const float* cs3 = (const float*)d_in[5];
    const float* c3  = (const float*)d_in[6];
    const float* s3v = (const float*)d_in[7];
    const float* cc3 = (const float*)d_in[8];
    const float* sc3 = (const float*)d_in[9];
    const float* cs4 = (const float*)d_in[10];
    const float* c4  = (const float*)d_in[11];
    const float* s4v = (const float*)d_in[12];
    const float* cc4 = (const float*)d_in[13];
    const float* sc4 = (const float*)d_in[14];

    const int B = 4;
    float* ws = (float*)d_ws;
    size_t fo = 0;
    auto allocF = [&](size_t n) { float* p = ws + fo; fo += n; return p; };

    float* lossp = allocF(4);
    float* c2m = allocF(B * 256);  float* c2r = allocF(B * 256);
    float* q2m = allocF(B * 448);  float* q2r = allocF(B * 448);
    float* k2m = allocF(B * 448);  float* k2r = allocF(B * 448);
    float* c3m = allocF(B * 512);  float* c3r = allocF(B * 512);
    float* q3m = allocF(B * 960);  float* q3r = allocF(B * 960);
    float* k3m = allocF(B * 960);  float* k3r = allocF(B * 960);
    float* c4m = allocF(B * 512);  float* c4r = allocF(B * 512);
    float* q4m = allocF(B * 1472); float* q4r = allocF(B * 1472);
    float* k4m = allocF(B * 1472); float* k4r = allocF(B * 1472);
    size_t zeroBytes = fo * sizeof(float);

    // partial-state buffers (shared across scales; stream-ordered reuse)
    float* Pm = allocF(32768);
    float* Pl = allocF(32768);
    float* PM = allocF(8388608);
    float* PS = allocF(8388608);

    // bf16 arena (16B aligned), reused per scale
    size_t arenaOff = ((fo * 4 + 15) & ~(size_t)15) / 2;
    ushort_t* arena = (ushort_t*)d_ws + arenaOff;
    const size_t arenaShorts = 41943040;   // max per-scale need (scale 2)
    size_t need = arenaOff * 2 + arenaShorts * 2;
    const bool fast = (ws_size >= need);

    hipMemsetAsync(d_ws, 0, zeroBytes, stream);

    auto stats = [&](const float* x, float* sm, float* sq, int N, int Cn) {
        int chG  = (Cn + 255) / 256;
        int nPer = 256;
        int nG   = (N + nPer - 1) / nPer;
        hipLaunchKernelGGL(stat_partial, dim3(B * chG * nG), dim3(256), 0, stream,
                           x, sm, sq, N, Cn, chG, nG, nPer);
        int total = B * Cn;
        hipLaunchKernelGGL(stat_finalize, dim3((total + 255) / 256), dim3(256), 0, stream,
                           sm, sq, total, 1.0f / (float)N);
    };

    stats(c2,  c2m, c2r, 4096, 256);
    stats(cc2, q2m, q2r, 4096, 448);
    stats(sc2, k2m, k2r, 4096, 448);
    stats(c3,  c3m, c3r, 1024, 512);
    stats(cc3, q3m, q3r, 1024, 960);
    stats(sc3, k3m, k3r, 1024, 960);
    stats(c4,  c4m, c4r, 256, 512);
    stats(cc4, q4m, q4r, 256, 1472);
    stats(sc4, k4m, k4r, 256, 1472);

    if (fast) {
        // ---- scale 2: N=4096, Cc=448, C=256, CSPLIT=1 (QREG), SPLIT=2 ----
        {
            size_t o = 0;
            auto aU = [&](size_t n) { ushort_t* p = arena + o; o += (n + 7) & ~(size_t)7; return p; };
            ushort_t *qh = aU((size_t)B*4096*448), *qlo = aU((size_t)B*4096*448);
            ushort_t *kh = aU((size_t)B*4096*448), *klo = aU((size_t)B*4096*448);
            ushort_t *vh = aU((size_t)B*4096*256), *uh = aU((size_t)B*4096*256), *ul = aU((size_t)B*4096*256);
            hipLaunchKernelGGL(norm_split, dim3(B*4096), dim3(256), 0, stream, cc2, q2m, q2r, qh, qlo, 4096, 448);
            hipLaunchKernelGGL(norm_split, dim3(B*4096), dim3(256), 0, stream, sc2, k2m, k2r, kh, klo, 4096, 448);
            hipLaunchKernelGGL((vsplit_t<512>), dim3(B*(256/64)*(4096/512)), dim3(256), 0, stream,
                               s2v, vh, uh, ul, 4096, 256);
            hipLaunchKernelGGL((flash_mfma<448, 256, 4096, 1, true, 2>), dim3(B*(4096/64)*2), dim3(256), 0, stream,
                               qh, qlo, kh, klo, vh, uh, ul, Pm, Pl, PM, PS);
            hipLaunchKernelGGL((combine_aat<256, 2>), dim3(B*4096/16), dim3(256), 0, stream,
                               Pm, Pl, PM, PS, c2, cs2, c2m, c2r, &lossp[0], 4096);
        }
        // ---- scale 3: N=1024, Cc=960, C=512, CSPLIT=2, SPLIT=4 ----
        {
            size_t o = 0;
            auto aU = [&](size_t n) { ushort_t* p = arena + o; o += (n + 7) & ~(size_t)7; return p; };
            ushort_t *qh = aU((size_t)B*1024*960), *qlo = aU((size_t)B*1024*960);
            ushort_t *kh = aU((size_t)B*1024*960), *klo = aU((size_t)B*1024*960);
            ushort_t *vh = aU((size_t)B*1024*512), *uh = aU((size_t)B*1024*512), *ul = aU((size_t)B*1024*512);
            hipLaunchKernelGGL(norm_split, dim3(B*1024), dim3(256), 0, stream, cc3, q3m, q3r, qh, qlo, 1024, 960);
            hipLaunchKernelGGL(norm_split, dim3(B*1024), dim3(256), 0, stream, sc3, k3m, k3r, kh, klo, 1024, 960);
            hipLaunchKernelGGL((vsplit_t<512>), dim3(B*(512/64)*(1024/512)), dim3(256), 0, stream,
                               s3v, vh, uh, ul, 1024, 512);
            hipLaunchKernelGGL((flash_mfma<960, 512, 1024, 2, false, 4>), dim3(B*(1024/32)*4), dim3(256), 0, stream,
                               qh, qlo, kh, klo, vh, uh, ul, Pm, Pl, PM, PS);
            hipLaunchKernelGGL((combine_aat<512, 4>), dim3(B*1024/16), dim3(256), 0, stream,
                               Pm, Pl, PM, PS, c3, cs3, c3m, c3r, &lossp[1], 1024);
        }
        // ---- scale 4: N=256, Cc=1472, C=512, CSPLIT=2, SPLIT=4 ----
        {
            size_t o = 0;
            auto aU = [&](size_t n) { ushort_t* p = arena + o; o += (n + 7) & ~(size_t)7; return p; };
            ushort_t *qh = aU((size_t)B*256*1472), *qlo = aU((size_t)B*256*1472);
            ushort_t *kh = aU((size_t)B*256*1472), *klo = aU((size_t)B*256*1472);
            ushort_t *vh = aU((size_t)B*256*512), *uh = aU((size_t)B*256*512), *ul = aU((size_t)B*256*512);
            hipLaunchKernelGGL(norm_split, dim3(B*256), dim3(256), 0, stream, cc4, q4m, q4r, qh, qlo, 256, 1472);
            hipLaunchKernelGGL(norm_split, dim3(B*256), dim3(256), 0, stream, sc4, k4m, k4r, kh, klo, 256, 1472);
            hipLaunchKernelGGL((vsplit_t<256>), dim3(B*(512/64)*(256/256)), dim3(256), 0, stream,
                               s4v, vh, uh, ul, 256, 512);
            hipLaunchKernelGGL((flash_mfma<1472, 512, 256, 2, false, 4>), dim3(B*(256/32)*4), dim3(256), 0, stream,
                               qh, qlo, kh, klo, vh, uh, ul, Pm, Pl, PM, PS);
            hipLaunchKernelGGL((combine_aat<512, 4>), dim3(B*256/16), dim3(256), 0, stream,
                               Pm, Pl, PM, PS, c4, cs4, c4m, c4r, &lossp[2], 256);
        }
    } else {
        hipLaunchKernelGGL((flash_aat<7, 4, 4>), dim3(B * 4096 / 16), dim3(256), 0, stream,
                           cc2, sc2, s2v, c2, cs2, q2m, q2r, k2m, k2r, c2m, c2r, &lossp[0], 4096);
        hipLaunchKernelGGL((flash_aat<15, 8, 2>), dim3(B * 1024 / 8), dim3(256), 0, stream,
                           cc3, sc3, s3v, c3, cs3, q3m, q3r, k3m, k3r, c3m, c3r, &lossp[1], 1024);
        hipLaunchKernelGGL((flash_aat<23, 8, 2>), dim3(B * 256 / 8), dim3(256), 0, stream,
                           cc4, sc4, s4v, c4, cs4, q4m, q4r, k4m, k4r, c4m, c4r, &lossp[2], 256);
    }

    hipLaunchKernelGGL(combine_loss, dim3(1), dim3(1), 0, stream,
                       lossp, (float*)d_out,
                       1.0f / (4.0f * 4096.0f * 256.0f),
                       1.0f / (4.0f * 1024.0f * 512.0f),
                       1.0f / (4.0f * 256.0f * 512.0f));
}

// Round 4
// 1733.616 us; speedup vs baseline: 5.2068x; 1.2881x over previous
//
#include <hip/hip_runtime.h>
#include <math.h>

#define EPS_NORM 1e-5f
#define EPS_VAR  1e-9f

typedef unsigned short ushort_t;
typedef __attribute__((ext_vector_type(4))) float f32x4;
typedef _Float16 half8 __attribute__((ext_vector_type(8)));

#define MFMAH(a, b, c) __builtin_amdgcn_mfma_f32_16x16x32_f16((a), (b), (c), 0, 0, 0)

// ---------------------------------------------------------------------------
// fp16 helpers
// ---------------------------------------------------------------------------
__device__ inline ushort_t f16_bits(float x) {
    _Float16 h = (_Float16)x;
    ushort_t u;
    __builtin_memcpy(&u, &h, 2);
    return u;
}
__device__ inline half8 ldh(const ushort_t* p) {   // 16B-aligned load
    half8 h;
    __builtin_memcpy(&h, p, 16);
    return h;
}
__device__ inline uint4 pack8(const ushort_t* s) {
    uint4 r;
    r.x = (unsigned)s[0] | ((unsigned)s[1] << 16);
    r.y = (unsigned)s[2] | ((unsigned)s[3] << 16);
    r.z = (unsigned)s[4] | ((unsigned)s[5] << 16);
    r.w = (unsigned)s[6] | ((unsigned)s[7] << 16);
    return r;
}

// ---------------------------------------------------------------------------
// Stage 1: per-(batch, channel) sum / sumsq over spatial axis (split-N atomic)
// ---------------------------------------------------------------------------
__global__ void __launch_bounds__(256) stat_partial(
    const float* __restrict__ x, float* __restrict__ sum, float* __restrict__ sumsq,
    int N, int Cn, int chG, int nG, int nPer)
{
    int bx = blockIdx.x;
    int b  = bx / (chG * nG);
    int r  = bx % (chG * nG);
    int cg = r / nG;
    int ng = r % nG;
    int ch = cg * 256 + threadIdx.x;
    if (ch >= Cn) return;
    int n0 = ng * nPer;
    int n1 = min(n0 + nPer, N);
    const float* p = x + (long)(b * N) * Cn + ch;
    float s = 0.f, ss = 0.f;
    for (int n = n0; n < n1; ++n) {
        float v = p[(long)n * Cn];
        s += v;
        ss = fmaf(v, v, ss);
    }
    atomicAdd(&sum[b * Cn + ch], s);
    atomicAdd(&sumsq[b * Cn + ch], ss);
}

__global__ void __launch_bounds__(256) stat_finalize(
    float* __restrict__ sum, float* __restrict__ sumsq, int total, float invN)
{
    int i = blockIdx.x * blockDim.x + threadIdx.x;
    if (i >= total) return;
    float m = sum[i] * invN;
    float v = sumsq[i] * invN - m * m;
    sum[i]   = m;
    sumsq[i] = rsqrtf(v + EPS_NORM);
}

// ---------------------------------------------------------------------------
// Prepass: normalize X (B,N,Cn) -> fp16 (same layout)
// ---------------------------------------------------------------------------
__global__ void __launch_bounds__(256) norm_f16(
    const float* __restrict__ x, const float* __restrict__ mean,
    const float* __restrict__ rstd, ushort_t* __restrict__ out, int N, int Cn)
{
    int bn = blockIdx.x;          // b*N + n
    int b  = bn / N;
    long base = (long)bn * Cn;
    for (int ch = threadIdx.x; ch < Cn; ch += 256) {
        float v = (x[base + ch] - mean[b * Cn + ch]) * rstd[b * Cn + ch];
        out[base + ch] = f16_bits(v);
    }
}

// ---------------------------------------------------------------------------
// Prepass: V (B,N,C) -> transposed (B,C,N) fp16 of v and v^2
// ---------------------------------------------------------------------------
template<int KSEG>
__global__ void __launch_bounds__(256) vsplit_t(
    const float* __restrict__ v,
    ushort_t* __restrict__ vt, ushort_t* __restrict__ v2t, int N, int C)
{
    int cPB = C / 64, nSeg = N / KSEG;
    int bid = blockIdx.x;
    int b   = bid / (cPB * nSeg);
    int rem = bid % (cPB * nSeg);
    int cb  = rem / nSeg;
    int ns  = rem % nSeg;
    int ch  = cb * 64 + (threadIdx.x & 63);
    const int KL = KSEG / 4;
    int k0  = ns * KSEG + (threadIdx.x >> 6) * KL;
    long obase = ((long)b * C + ch) * N;
    for (int k = k0; k < k0 + KL; k += 8) {
        ushort_t h8[8], h28[8];
#pragma unroll
        for (int i = 0; i < 8; ++i) {
            float x  = v[((long)b * N + k + i) * C + ch];
            h8[i]  = f16_bits(x);
            h28[i] = f16_bits(x * x);
        }
        *(uint4*)(vt  + obase + k) = pack8(h8);
        *(uint4*)(v2t + obase + k) = pack8(h28);
    }
}

// ---------------------------------------------------------------------------
// Cooperative tile stagers: global (stride gstride) -> LDS (stride 72 shorts)
// ---------------------------------------------------------------------------
__device__ inline void stage64(const ushort_t* __restrict__ g, long rowBase,
                               int gstride, int col0, ushort_t* l, int tid)
{
    int r  = tid >> 2;            // 0..63
    int cs = (tid & 3) << 4;      // 0,16,32,48
    const ushort_t* gp = g + (rowBase + r) * (long)gstride + col0 + cs;
    uint4 a  = *(const uint4*)gp;
    uint4 bb = *(const uint4*)(gp + 8);
    ushort_t* lp = l + r * 72 + cs;
    *(uint4*)lp       = a;
    *(uint4*)(lp + 8) = bb;
}
__device__ inline void stage32(const ushort_t* __restrict__ g, long rowBase,
                               int gstride, int col0, ushort_t* l, int tid)
{
    int r  = tid >> 3;            // 0..31
    int cs = (tid & 7) << 3;      // 0,8,..,56 (shorts)
    const ushort_t* gp = g + (rowBase + r) * (long)gstride + col0 + cs;
    uint4 a = *(const uint4*)gp;
    *(uint4*)(l + r * 72 + cs) = a;
}

// ---------------------------------------------------------------------------
// Flash MFMA (fp16 single-pass) with key-split and optional C-split.
// CSPLIT=1 (QREG): 4 waves = 4 q-stripes, 64 rows/block, SLABS=4.
// CSPLIT=2: wave pairs share a q-stripe (32 rows), each half of C, SLABS=6.
// QK: 4 K-chunks (+Q) staged per barrier pair. PV: 4 V/V2 slabs per pair.
// ---------------------------------------------------------------------------
template<int Cc, int C, int N, int CSPLIT, bool QREG, int SPLIT, int SLABS>
__global__ void __launch_bounds__(256, 2) flash_mfma(
    const ushort_t* __restrict__ Qh, const ushort_t* __restrict__ Kh,
    const ushort_t* __restrict__ Vth, const ushort_t* __restrict__ V2th,
    float* __restrict__ Pmo, float* __restrict__ Plo,
    float* __restrict__ PMo, float* __restrict__ PSo)
{
    constexpr int KC      = Cc / 64;
    constexpr int VC      = C / 64;
    constexpr int VCW     = VC / CSPLIT;
    constexpr int CTCW    = 4 * VCW;
    constexpr int STRIPES = 4 / CSPLIT;
    constexpr int BROWS   = 16 * STRIPES;
    constexpr int QB      = N / BROWS;
    constexpr int NKT     = (N / 64) / SPLIT;
    constexpr int NKS     = QREG ? (Cc / 32) : 1;
    constexpr int NGRP    = (KC + 3) / 4;

    __shared__ ushort_t smem[SLABS * 4608 + 4 * 1152];
    const int tid  = threadIdx.x;
    const int lane = tid & 63;
    const int w    = tid >> 6;
    const int l15  = lane & 15;
    const int quad = lane >> 4;

    const int bq = blockIdx.x / SPLIT;
    const int sp = blockIdx.x % SPLIT;
    const int b  = bq / QB;
    const int qb = bq % QB;
    const int ls  = w / CSPLIT;       // stripe within block
    const int ch2 = w % CSPLIT;       // channel half
    const int i0 = qb * BROWS + ls * 16;
    const long po = (long)(b * (N / 16) + qb * STRIPES + ls) * SPLIT + sp;
    ushort_t* Pw = smem + SLABS * 4608 + w * 1152;

    half8 qf[NKS];
    if constexpr (QREG) {
        const ushort_t* q1 = Qh + ((long)(b * N + i0 + l15)) * Cc + quad * 8;
#pragma unroll
        for (int ks = 0; ks < NKS; ++ks) qf[ks] = ldh(q1 + ks * 32);
    }

    float m_r[4], l_r[4];
    f32x4 Mac[CTCW], Sac[CTCW];
#pragma unroll
    for (int r = 0; r < 4; ++r) { m_r[r] = -1e30f; l_r[r] = 0.f; }
#pragma unroll
    for (int ct = 0; ct < CTCW; ++ct)
#pragma unroll
        for (int r = 0; r < 4; ++r) { Mac[ct][r] = 0.f; Sac[ct][r] = 0.f; }

    for (int kt = sp * NKT; kt < sp * NKT + NKT; ++kt) {
        const long krow = (long)b * N + kt * 64;

        f32x4 S[4];
#pragma unroll
        for (int ct = 0; ct < 4; ++ct)
#pragma unroll
            for (int r = 0; r < 4; ++r) S[ct][r] = 0.f;

        // ---- QK: groups of up to 4 chunks per barrier pair ----
#pragma unroll
        for (int grp = 0; grp < NGRP; ++grp) {
            const int g0 = grp * 4;
            const int gn = (KC - g0 < 4) ? (KC - g0) : 4;
            __syncthreads();
#pragma unroll
            for (int j = 0; j < 4; ++j) if (j < gn) {
                stage64(Kh, krow, Cc, (g0 + j) * 64, smem + j * 4608, tid);
                if constexpr (!QREG)
                    stage32(Qh, (long)b * N + qb * BROWS, Cc, (g0 + j) * 64,
                            smem + 4 * 4608 + j * 2304, tid);
            }
            __syncthreads();
#pragma unroll
            for (int j = 0; j < 4; ++j) if (j < gn) {
#pragma unroll
                for (int ks = 0; ks < 2; ++ks) {
                    half8 a;
                    if constexpr (QREG) a = qf[(g0 + j) * 2 + ks];
                    else a = ldh(smem + 4 * 4608 + j * 2304 +
                                 (ls * 16 + l15) * 72 + ks * 32 + quad * 8);
#pragma unroll
                    for (int ct = 0; ct < 4; ++ct) {
                        half8 bf = ldh(smem + j * 4608 +
                                       (ct * 16 + l15) * 72 + ks * 32 + quad * 8);
                        S[ct] = MFMAH(a, bf, S[ct]);
                    }
                }
            }
        }

        // ---- online softmax (C/D layout: row=quad*4+r, col=l15) ----
        float mx[4];
#pragma unroll
        for (int r = 0; r < 4; ++r)
            mx[r] = fmaxf(fmaxf(S[0][r], S[1][r]), fmaxf(S[2][r], S[3][r]));
#pragma unroll
        for (int off = 1; off <= 8; off <<= 1)
#pragma unroll
            for (int r = 0; r < 4; ++r)
                mx[r] = fmaxf(mx[r], __shfl_xor(mx[r], off, 64));
        float corr[4];
#pragma unroll
        for (int r = 0; r < 4; ++r) {
            float mn = fmaxf(m_r[r], mx[r]);
            corr[r] = __expf(m_r[r] - mn);
            m_r[r]  = mn;
            l_r[r] *= corr[r];
        }
#pragma unroll
        for (int ct = 0; ct < CTCW; ++ct)
#pragma unroll
            for (int r = 0; r < 4; ++r) { Mac[ct][r] *= corr[r]; Sac[ct][r] *= corr[r]; }

        float ps[4] = {0.f, 0.f, 0.f, 0.f};
#pragma unroll
        for (int ct = 0; ct < 4; ++ct)
#pragma unroll
            for (int r = 0; r < 4; ++r) {
                float p = __expf(S[ct][r] - m_r[r]);
                ps[r] += p;
                Pw[(quad * 4 + r) * 72 + ct * 16 + l15] = f16_bits(p);
            }
#pragma unroll
        for (int off = 1; off <= 8; off <<= 1)
#pragma unroll
            for (int r = 0; r < 4; ++r) ps[r] += __shfl_xor(ps[r], off, 64);
#pragma unroll
        for (int r = 0; r < 4; ++r) l_r[r] += ps[r];

        // ---- PV / PV^2 (P is per-wave in LDS; no barrier needed for it) ----
        if constexpr (CSPLIT == 1) {
#pragma unroll
            for (int pg = 0; pg < VC / 2; ++pg) {
                __syncthreads();
                stage64(Vth,  (long)b * C + (pg * 2 + 0) * 64, N, kt * 64, smem + 0 * 4608, tid);
                stage64(Vth,  (long)b * C + (pg * 2 + 1) * 64, N, kt * 64, smem + 1 * 4608, tid);
                stage64(V2th, (long)b * C + (pg * 2 + 0) * 64, N, kt * 64, smem + 2 * 4608, tid);
                stage64(V2th, (long)b * C + (pg * 2 + 1) * 64, N, kt * 64, smem + 3 * 4608, tid);
                __syncthreads();
#pragma unroll
                for (int ks = 0; ks < 2; ++ks) {
                    half8 pf = ldh(Pw + l15 * 72 + ks * 32 + quad * 8);
#pragma unroll
                    for (int lv = 0; lv < 2; ++lv)
#pragma unroll
                        for (int ct = 0; ct < 4; ++ct) {
                            const int vo = (ct * 16 + l15) * 72 + ks * 32 + quad * 8;
                            half8 vh = ldh(smem + lv * 4608 + vo);
                            half8 uh = ldh(smem + (2 + lv) * 4608 + vo);
                            const int ci = (pg * 2 + lv) * 4 + ct;
                            Mac[ci] = MFMAH(pf, vh, Mac[ci]);
                            Sac[ci] = MFMAH(pf, uh, Sac[ci]);
                        }
                }
            }
        } else {
#pragma unroll
            for (int vcl = 0; vcl < VCW; ++vcl) {
                __syncthreads();
                stage64(Vth,  (long)b * C + (0 * VCW + vcl) * 64, N, kt * 64, smem + 0 * 4608, tid);
                stage64(V2th, (long)b * C + (0 * VCW + vcl) * 64, N, kt * 64, smem + 1 * 4608, tid);
                stage64(Vth,  (long)b * C + (1 * VCW + vcl) * 64, N, kt * 64, smem + 2 * 4608, tid);
                stage64(V2th, (long)b * C + (1 * VCW + vcl) * 64, N, kt * 64, smem + 3 * 4608, tid);
                __syncthreads();
                const ushort_t* Bv = smem + 2 * ch2 * 4608;
#pragma unroll
                for (int ks = 0; ks < 2; ++ks) {
                    half8 pf = ldh(Pw + l15 * 72 + ks * 32 + quad * 8);
#pragma unroll
                    for (int ct = 0; ct < 4; ++ct) {
                        const int vo = (ct * 16 + l15) * 72 + ks * 32 + quad * 8;
                        half8 vh = ldh(Bv + vo);
                        half8 uh = ldh(Bv + 4608 + vo);
                        const int ci = vcl * 4 + ct;
                        Mac[ci] = MFMAH(pf, vh, Mac[ci]);
                        Sac[ci] = MFMAH(pf, uh, Sac[ci]);
                    }
                }
            }
        }
    }

    // ---- dump partial state ----
    if (ch2 == 0 && l15 == 0) {
#pragma unroll
        for (int r = 0; r < 4; ++r) {
            Pmo[po * 16 + quad * 4 + r] = m_r[r];
            Plo[po * 16 + quad * 4 + r] = l_r[r];
        }
    }
    const int chb = ch2 * (C / CSPLIT);
#pragma unroll
    for (int ct = 0; ct < CTCW; ++ct)
#pragma unroll
        for (int r = 0; r < 4; ++r) {
            long idx = (po * 16 + quad * 4 + r) * C + chb + ct * 16 + l15;
            PMo[idx] = Mac[ct][r];
            PSo[idx] = Sac[ct][r];
        }
}

// ---------------------------------------------------------------------------
// Combine: merge SPLIT flash partials per 16-row stripe, fused epilogue + MSE.
// ---------------------------------------------------------------------------
template<int C, int SPLIT>
__global__ void __launch_bounds__(256) combine_aat(
    const float* __restrict__ Pm, const float* __restrict__ Pl,
    const float* __restrict__ PM, const float* __restrict__ PS,
    const float* __restrict__ CT, const float* __restrict__ CS,
    const float* __restrict__ cmean, const float* __restrict__ crstd,
    float* __restrict__ loss, int N)
{
    __shared__ float wS[SPLIT][16];
    __shared__ float invL[16];
    __shared__ float red[4];
    const int pi = blockIdx.x;
    const int nb = N / 16;
    const int b  = pi / nb;
    const long g0 = (long)b * N + (long)(pi % nb) * 16;
    const int tid = threadIdx.x;

    if (tid < 16) {
        float m = -1e30f;
#pragma unroll
        for (int s = 0; s < SPLIT; ++s)
            m = fmaxf(m, Pm[((long)pi * SPLIT + s) * 16 + tid]);
        float L = 0.f;
#pragma unroll
        for (int s = 0; s < SPLIT; ++s) {
            float e = __expf(Pm[((long)pi * SPLIT + s) * 16 + tid] - m);
            wS[s][tid] = e;
            L = fmaf(e, Pl[((long)pi * SPLIT + s) * 16 + tid], L);
        }
        invL[tid] = 1.f / L;
    }
    __syncthreads();

    float acc = 0.f;
    for (int e = tid; e < 16 * C; e += 256) {
        const int r  = e / C;
        const int ch = e % C;
        float Ms = 0.f, Ss = 0.f;
#pragma unroll
        for (int s = 0; s < SPLIT; ++s) {
            const long q = (((long)pi * SPLIT + s) * 16 + r) * C + ch;
            Ms = fmaf(wS[s][r], PM[q], Ms);
            Ss = fmaf(wS[s][r], PS[q], Ss);
        }
        const float M  = Ms * invL[r];
        const float S2 = Ss * invL[r] - M * M;
        const float S  = sqrtf(fmaxf(S2, EPS_VAR));
        const float nc = (CT[(g0 + r) * C + ch] - cmean[b * C + ch]) * crstd[b * C + ch];
        const float d  = CS[(g0 + r) * C + ch] - (S * nc + M);
        acc = fmaf(d, d, acc);
    }
#pragma unroll
    for (int off = 1; off <= 32; off <<= 1) acc += __shfl_xor(acc, off, 64);
    if ((tid & 63) == 0) red[tid >> 6] = acc;
    __syncthreads();
    if (tid == 0) atomicAdd(loss, red[0] + red[1] + red[2] + red[3]);
}

// ---------------------------------------------------------------------------
// Fallback scalar flash kernel (only if ws_size too small)
// ---------------------------------------------------------------------------
template<int CCL, int CL, int NQ>
__global__ void __launch_bounds__(256) flash_aat(
    const float* __restrict__ Q, const float* __restrict__ K, const float* __restrict__ V,
    const float* __restrict__ CT, const float* __restrict__ CS,
    const float* __restrict__ qmean, const float* __restrict__ qrstd,
    const float* __restrict__ kmean, const float* __restrict__ krstd,
    const float* __restrict__ cmean, const float* __restrict__ crstd,
    float* __restrict__ loss, int N)
{
    constexpr int CC   = CCL * 64;
    constexpr int C    = CL * 64;
    constexpr int ROWS = 4 * NQ;
    const int lane = threadIdx.x & 63;
    const int wave = threadIdx.x >> 6;
    const int rowBlocks = N / ROWS;
    const int b  = blockIdx.x / rowBlocks;
    const int rb = blockIdx.x % rowBlocks;
    const int i0 = rb * ROWS + wave * NQ;

    float kmu[CCL], krs[CCL];
#pragma unroll
    for (int t = 0; t < CCL; ++t) {
        int ch = lane + 64 * t;
        kmu[t] = kmean[b * CC + ch];
        krs[t] = krstd[b * CC + ch];
    }
    float q[NQ][CCL];
#pragma unroll
    for (int qi = 0; qi < NQ; ++qi) {
        long base = (long)(b * N + i0 + qi) * CC;
#pragma unroll
        for (int t = 0; t < CCL; ++t) {
            int ch = lane + 64 * t;
            q[qi][t] = (Q[base + ch] - qmean[b * CC + ch]) * qrstd[b * CC + ch];
        }
    }
    float mval[NQ], lsum[NQ];
    float Macc[NQ][CL], Sacc[NQ][CL];
#pragma unroll
    for (int qi = 0; qi < NQ; ++qi) {
        mval[qi] = -1e30f; lsum[qi] = 0.f;
#pragma unroll
        for (int t = 0; t < CL; ++t) { Macc[qi][t] = 0.f; Sacc[qi][t] = 0.f; }
    }
    for (int j = 0; j < N; ++j) {
        long kb = (long)(b * N + j) * CC;
        float dot[NQ];
#pragma unroll
        for (int qi = 0; qi < NQ; ++qi) dot[qi] = 0.f;
#pragma unroll
        for (int t = 0; t < CCL; ++t) {
            float kv = (K[kb + lane + 64 * t] - kmu[t]) * krs[t];
#pragma unroll
            for (int qi = 0; qi < NQ; ++qi) dot[qi] = fmaf(q[qi][t], kv, dot[qi]);
        }
#pragma unroll
        for (int off = 32; off > 0; off >>= 1)
#pragma unroll
            for (int qi = 0; qi < NQ; ++qi) dot[qi] += __shfl_xor(dot[qi], off, 64);
        long vb = (long)(b * N + j) * C;
        float vv[CL];
#pragma unroll
        for (int t = 0; t < CL; ++t) vv[t] = V[vb + lane + 64 * t];
#pragma unroll
        for (int qi = 0; qi < NQ; ++qi) {
            float s = dot[qi];
            float p;
            if (s > mval[qi]) {
                float cr2 = __expf(mval[qi] - s);
                lsum[qi] *= cr2;
#pragma unroll
                for (int t = 0; t < CL; ++t) { Macc[qi][t] *= cr2; Sacc[qi][t] *= cr2; }
                mval[qi] = s; p = 1.f;
            } else p = __expf(s - mval[qi]);
            lsum[qi] += p;
#pragma unroll
            for (int t = 0; t < CL; ++t) {
                float pv = p * vv[t];
                Macc[qi][t] += pv;
                Sacc[qi][t] = fmaf(pv, vv[t], Sacc[qi][t]);
            }
        }
    }
    float acc = 0.f;
#pragma unroll
    for (int qi = 0; qi < NQ; ++qi) {
        float inv_l = 1.f / lsum[qi];
        long base = (long)(b * N + i0 + qi) * C;
#pragma unroll
        for (int t = 0; t < CL; ++t) {
            int ch = lane + 64 * t;
            float M  = Macc[qi][t] * inv_l;
            float S2 = Sacc[qi][t] * inv_l - M * M;
            float S  = sqrtf(fmaxf(S2, EPS_VAR));
            float nc = (CT[base + ch] - cmean[b * C + ch]) * crstd[b * C + ch];
            float d  = CS[base + ch] - (S * nc + M);
            acc = fmaf(d, d, acc);
        }
    }
#pragma unroll
    for (int off = 32; off > 0; off >>= 1) acc += __shfl_xor(acc, off, 64);
    if (lane == 0) atomicAdd(loss, acc);
}

__global__ void combine_loss(const float* __restrict__ lp, float* __restrict__ out,
                             float s0, float s1, float s2)
{
    out[0] = lp[0] * s0 + lp[1] * s1 + lp[2] * s2;
}

// ---------------------------------------------------------------------------
extern "C" void kernel_launch(void* const* d_in, const int* in_sizes, int n_in,
                              void* d_out, int out_size, void* d_ws, size_t ws_size,
                              hipStream_t stream)
{
    const float* cs2 = (const float*)d_in[0];
    const float* c2  = (const float*)d_in[1];
    const float* s2v = (const float*)d_in[2];
    const float* cc2 = (const float*)d_in[3];
    const float* sc2 = (const float*)d_in[4];
    const float* cs3 = (const float*)d_in[5];
    const float* c3  = (const float*)d_in[6];
    const float* s3v = (const float*)d_in[7];
    const float* cc3 = (const float*)d_in[8];
    const float* sc3 = (const float*)d_in[9];
    const float* cs4 = (const float*)d_in[10];
    const float* c4  = (const float*)d_in[11];
    const float* s4v = (const float*)d_in[12];
    const float* cc4 = (const float*)d_in[13];
    const float* sc4 = (const float*)d_in[14];

    const int B = 4;
    float* ws = (float*)d_ws;
    size_t fo = 0;
    auto allocF = [&](size_t n) { float* p = ws + fo; fo += n; return p; };

    float* lossp = allocF(4);
    float* c2m = allocF(B * 256);  float* c2r = allocF(B * 256);
    float* q2m = allocF(B * 448);  float* q2r = allocF(B * 448);
    float* k2m = allocF(B * 448);  float* k2r = allocF(B * 448);
    float* c3m = allocF(B * 512);  float* c3r = allocF(B * 512);
    float* q3m = allocF(B * 960);  float* q3r = allocF(B * 960);
    float* k3m = allocF(B * 960);  float* k3r = allocF(B * 960);
    float* c4m = allocF(B * 512);  float* c4r = allocF(B * 512);
    float* q4m = allocF(B * 1472); float* q4r = allocF(B * 1472);
    float* k4m = allocF(B * 1472); float* k4r = allocF(B * 1472);
    size_t zeroBytes = fo * sizeof(float);

    // partial-state buffers (shared across scales; stream-ordered reuse)
    float* Pm = allocF(32768);
    float* Pl = allocF(32768);
    float* PM = allocF(8388608);
    float* PS = allocF(8388608);

    // fp16 arena (16B aligned), reused per scale
    size_t arenaOff = ((fo * 4 + 15) & ~(size_t)15) / 2;
    ushort_t* arena = (ushort_t*)d_ws + arenaOff;
    const size_t arenaShorts = 23068672;   // max per-scale need (scale 2)
    size_t need = arenaOff * 2 + arenaShorts * 2;
    const bool fast = (ws_size >= need);

    hipMemsetAsync(d_ws, 0, zeroBytes, stream);

    auto stats = [&](const float* x, float* sm, float* sq, int N, int Cn) {
        int chG  = (Cn + 255) / 256;
        int nPer = 256;
        int nG   = (N + nPer - 1) / nPer;
        hipLaunchKernelGGL(stat_partial, dim3(B * chG * nG), dim3(256), 0, stream,
                           x, sm, sq, N, Cn, chG, nG, nPer);
        int total = B * Cn;
        hipLaunchKernelGGL(stat_finalize, dim3((total + 255) / 256), dim3(256), 0, stream,
                           sm, sq, total, 1.0f / (float)N);
    };

    stats(c2,  c2m, c2r, 4096, 256);
    stats(cc2, q2m, q2r, 4096, 448);
    stats(sc2, k2m, k2r, 4096, 448);
    stats(c3,  c3m, c3r, 1024, 512);
    stats(cc3, q3m, q3r, 1024, 960);
    stats(sc3, k3m, k3r, 1024, 960);
    stats(c4,  c4m, c4r, 256, 512);
    stats(cc4, q4m, q4r, 256, 1472);
    stats(sc4, k4m, k4r, 256, 1472);

    if (fast) {
        // ---- scale 2: N=4096, Cc=448, C=256, CSPLIT=1 (QREG), SPLIT=2 ----
        {
            size_t o = 0;
            auto aU = [&](size_t n) { ushort_t* p = arena + o; o += (n + 7) & ~(size_t)7; return p; };
            ushort_t *qh = aU((size_t)B*4096*448), *kh = aU((size_t)B*4096*448);
            ushort_t *vh = aU((size_t)B*4096*256), *uh = aU((size_t)B*4096*256);
            hipLaunchKernelGGL(norm_f16, dim3(B*4096), dim3(256), 0, stream, cc2, q2m, q2r, qh, 4096, 448);
            hipLaunchKernelGGL(norm_f16, dim3(B*4096), dim3(256), 0, stream, sc2, k2m, k2r, kh, 4096, 448);
            hipLaunchKernelGGL((vsplit_t<512>), dim3(B*(256/64)*(4096/512)), dim3(256), 0, stream,
                               s2v, vh, uh, 4096, 256);
            hipLaunchKernelGGL((flash_mfma<448, 256, 4096, 1, true, 2, 4>), dim3(B*(4096/64)*2), dim3(256), 0, stream,
                               qh, kh, vh, uh, Pm, Pl, PM, PS);
            hipLaunchKernelGGL((combine_aat<256, 2>), dim3(B*4096/16), dim3(256), 0, stream,
                               Pm, Pl, PM, PS, c2, cs2, c2m, c2r, &lossp[0], 4096);
        }
        // ---- scale 3: N=1024, Cc=960, C=512, CSPLIT=2, SPLIT=4 ----
        {
            size_t o = 0;
            auto aU = [&](size_t n) { ushort_t* p = arena + o; o += (n + 7) & ~(size_t)7; return p; };
            ushort_t *qh = aU((size_t)B*1024*960), *kh = aU((size_t)B*1024*960);
            ushort_t *vh = aU((size_t)B*1024*512), *uh = aU((size_t)B*1024*512);
            hipLaunchKernelGGL(norm_f16, dim3(B*1024), dim3(256), 0, stream, cc3, q3m, q3r, qh, 1024, 960);
            hipLaunchKernelGGL(norm_f16, dim3(B*1024), dim3(256), 0, stream, sc3, k3m, k3r, kh, 1024, 960);
            hipLaunchKernelGGL((vsplit_t<512>), dim3(B*(512/64)*(1024/512)), dim3(256), 0, stream,
                               s3v, vh, uh, 1024, 512);
            hipLaunchKernelGGL((flash_mfma<960, 512, 1024, 2, false, 4, 6>), dim3(B*(1024/32)*4), dim3(256), 0, stream,
                               qh, kh, vh, uh, Pm, Pl, PM, PS);
            hipLaunchKernelGGL((combine_aat<512, 4>), dim3(B*1024/16), dim3(256), 0, stream,
                               Pm, Pl, PM, PS, c3, cs3, c3m, c3r, &lossp[1], 1024);
        }
        // ---- scale 4: N=256, Cc=1472, C=512, CSPLIT=2, SPLIT=4 ----
        {
            size_t o = 0;
            auto aU = [&](size_t n) { ushort_t* p = arena + o; o += (n + 7) & ~(size_t)7; return p; };
            ushort_t *qh = aU((size_t)B*256*1472), *kh = aU((size_t)B*256*1472);
            ushort_t *vh = aU((size_t)B*256*512), *uh = aU((size_t)B*256*512);
            hipLaunchKernelGGL(norm_f16, dim3(B*256), dim3(256), 0, stream, cc4, q4m, q4r, qh, 256, 1472);
            hipLaunchKernelGGL(norm_f16, dim3(B*256), dim3(256), 0, stream, sc4, k4m, k4r, kh, 256, 1472);
            hipLaunchKernelGGL((vsplit_t<256>), dim3(B*(512/64)*(256/256)), dim3(256), 0, stream,
                               s4v, vh, uh, 256, 512);
            hipLaunchKernelGGL((flash_mfma<1472, 512, 256, 2, false, 4, 6>), dim3(B*(256/32)*4), dim3(256), 0, stream,
                               qh, kh, vh, uh, Pm, Pl, PM, PS);
            hipLaunchKernelGGL((combine_aat<512, 4>), dim3(B*256/16), dim3(256), 0, stream,
                               Pm, Pl, PM, PS, c4, cs4, c4m, c4r, &lossp[2], 256);
        }
    } else {
        hipLaunchKernelGGL((flash_aat<7, 4, 4>), dim3(B * 4096 / 16), dim3(256), 0, stream,
                           cc2, sc2, s2v, c2, cs2, q2m, q2r, k2m, k2r, c2m, c2r, &lossp[0], 4096);
        hipLaunchKernelGGL((flash_aat<15, 8, 2>), dim3(B * 1024 / 8), dim3(256), 0, stream,
                           cc3, sc3, s3v, c3, cs3, q3m, q3r, k3m, k3r, c3m, c3r, &lossp[1], 1024);
        hipLaunchKernelGGL((flash_aat<23, 8, 2>), dim3(B * 256 / 8), dim3(256), 0, stream,
                           cc4, sc4, s4v, c4, cs4, q4m, q4r, k4m, k4r, c4m, c4r, &lossp[2], 256);
    }

    hipLaunchKernelGGL(combine_loss, dim3(1), dim3(1), 0, stream,
                       lossp, (float*)d_out,
                       1.0f / (4.0f * 4096.0f * 256.0f),
                       1.0f / (4.0f * 1024.0f * 512.0f),
                       1.0f / (4.0f * 256.0f * 512.0f));
}

// Round 5
// 1625.734 us; speedup vs baseline: 5.5523x; 1.0664x over previous
//
#include <hip/hip_runtime.h>
#include <math.h>

#define EPS_NORM 1e-5f
#define EPS_VAR  1e-9f

typedef unsigned short ushort_t;
typedef __attribute__((ext_vector_type(4))) float f32x4;
typedef _Float16 half8 __attribute__((ext_vector_type(8)));

#define MFMAH(a, b, c) __builtin_amdgcn_mfma_f32_16x16x32_f16((a), (b), (c), 0, 0, 0)

// ---------------------------------------------------------------------------
// fp16 helpers
// ---------------------------------------------------------------------------
__device__ inline ushort_t f16_bits(float x) {
    _Float16 h = (_Float16)x;
    ushort_t u;
    __builtin_memcpy(&u, &h, 2);
    return u;
}
__device__ inline half8 ldh(const ushort_t* p) {   // 16B-aligned load
    half8 h;
    __builtin_memcpy(&h, p, 16);
    return h;
}
__device__ inline uint4 pack8(const ushort_t* s) {
    uint4 r;
    r.x = (unsigned)s[0] | ((unsigned)s[1] << 16);
    r.y = (unsigned)s[2] | ((unsigned)s[3] << 16);
    r.z = (unsigned)s[4] | ((unsigned)s[5] << 16);
    r.w = (unsigned)s[6] | ((unsigned)s[7] << 16);
    return r;
}

// ---------------------------------------------------------------------------
// Stage 1: per-(batch, channel) sum / sumsq over spatial axis (split-N atomic)
// ---------------------------------------------------------------------------
__global__ void __launch_bounds__(256) stat_partial(
    const float* __restrict__ x, float* __restrict__ sum, float* __restrict__ sumsq,
    int N, int Cn, int chG, int nG, int nPer)
{
    int bx = blockIdx.x;
    int b  = bx / (chG * nG);
    int r  = bx % (chG * nG);
    int cg = r / nG;
    int ng = r % nG;
    int ch = cg * 256 + threadIdx.x;
    if (ch >= Cn) return;
    int n0 = ng * nPer;
    int n1 = min(n0 + nPer, N);
    const float* p = x + (long)(b * N) * Cn + ch;
    float s = 0.f, ss = 0.f;
    for (int n = n0; n < n1; ++n) {
        float v = p[(long)n * Cn];
        s += v;
        ss = fmaf(v, v, ss);
    }
    atomicAdd(&sum[b * Cn + ch], s);
    atomicAdd(&sumsq[b * Cn + ch], ss);
}

__global__ void __launch_bounds__(256) stat_finalize(
    float* __restrict__ sum, float* __restrict__ sumsq, int total, float invN)
{
    int i = blockIdx.x * blockDim.x + threadIdx.x;
    if (i >= total) return;
    float m = sum[i] * invN;
    float v = sumsq[i] * invN - m * m;
    sum[i]   = m;
    sumsq[i] = rsqrtf(v + EPS_NORM);
}

// ---------------------------------------------------------------------------
// Prepass: normalize X (B,N,Cn) -> fp16 (same layout)
// ---------------------------------------------------------------------------
__global__ void __launch_bounds__(256) norm_f16(
    const float* __restrict__ x, const float* __restrict__ mean,
    const float* __restrict__ rstd, ushort_t* __restrict__ out, int N, int Cn)
{
    int bn = blockIdx.x;          // b*N + n
    int b  = bn / N;
    long base = (long)bn * Cn;
    for (int ch = threadIdx.x; ch < Cn; ch += 256) {
        float v = (x[base + ch] - mean[b * Cn + ch]) * rstd[b * Cn + ch];
        out[base + ch] = f16_bits(v);
    }
}

// ---------------------------------------------------------------------------
// Prepass: V (B,N,C) -> transposed (B,C,N) fp16  (V^2 now squared in-kernel)
// ---------------------------------------------------------------------------
template<int KSEG>
__global__ void __launch_bounds__(256) vsplit_t(
    const float* __restrict__ v, ushort_t* __restrict__ vt, int N, int C)
{
    int cPB = C / 64, nSeg = N / KSEG;
    int bid = blockIdx.x;
    int b   = bid / (cPB * nSeg);
    int rem = bid % (cPB * nSeg);
    int cb  = rem / nSeg;
    int ns  = rem % nSeg;
    int ch  = cb * 64 + (threadIdx.x & 63);
    const int KL = KSEG / 4;
    int k0  = ns * KSEG + (threadIdx.x >> 6) * KL;
    long obase = ((long)b * C + ch) * N;
    for (int k = k0; k < k0 + KL; k += 8) {
        ushort_t h8[8];
#pragma unroll
        for (int i = 0; i < 8; ++i)
            h8[i] = f16_bits(v[((long)b * N + k + i) * C + ch]);
        *(uint4*)(vt + obase + k) = pack8(h8);
    }
}

// ---------------------------------------------------------------------------
// Cooperative tile stagers: global (stride gstride) -> LDS (stride 72 shorts)
// ---------------------------------------------------------------------------
__device__ inline void stage64(const ushort_t* __restrict__ g, long rowBase,
                               int gstride, int col0, ushort_t* l, int tid)
{
    int r  = tid >> 2;            // 0..63
    int cs = (tid & 3) << 4;      // 0,16,32,48
    const ushort_t* gp = g + (rowBase + r) * (long)gstride + col0 + cs;
    uint4 a  = *(const uint4*)gp;
    uint4 bb = *(const uint4*)(gp + 8);
    ushort_t* lp = l + r * 72 + cs;
    *(uint4*)lp       = a;
    *(uint4*)(lp + 8) = bb;
}
template<int BROWS>
__device__ inline void stageQ(const ushort_t* __restrict__ g, long rowBase,
                              int gstride, int col0, ushort_t* l, int tid)
{
    if (tid < BROWS * 8) {
        int r  = tid >> 3;
        int cs = (tid & 7) << 3;  // shorts
        uint4 a = *(const uint4*)(g + (rowBase + r) * (long)gstride + col0 + cs);
        *(uint4*)(l + r * 72 + cs) = a;
    }
}

// ---------------------------------------------------------------------------
// Flash MFMA (fp16) with key-split and C-split; lazy-rescale online softmax.
// CSPLIT=1 (QREG): 4 waves = 4 q-stripes of 16 rows (64 rows/block).
// CSPLIT=2: wave pairs share a 16-row stripe (32 rows/block), each half of C.
// CSPLIT=4: all 4 waves share one stripe (16 rows/block), each quarter of C.
// QK: KGRP K-chunks per barrier pair (s2: all 7). PV: 4 V-slabs per pair,
// V^2 squared in-register. P stored as f16 with values up to e^10 (lazy base).
// ---------------------------------------------------------------------------
template<int Cc, int C, int N, int CSPLIT, bool QREG, int SPLIT, int SLABS, int KGRP>
__global__ void __launch_bounds__(256, 2) flash_mfma(
    const ushort_t* __restrict__ Qh, const ushort_t* __restrict__ Kh,
    const ushort_t* __restrict__ Vth,
    float* __restrict__ Pmo, float* __restrict__ Plo,
    float* __restrict__ PMo, float* __restrict__ PSo)
{
    constexpr int KC      = Cc / 64;
    constexpr int VC      = C / 64;
    constexpr int VCW     = VC / CSPLIT;
    constexpr int CTCW    = 4 * VCW;
    constexpr int STRIPES = 4 / CSPLIT;
    constexpr int BROWS   = 16 * STRIPES;
    constexpr int QB      = N / BROWS;
    constexpr int TILES   = N / 64;
    constexpr int NKT     = TILES / SPLIT;
    constexpr int NKS     = QREG ? (Cc / 32) : 1;
    constexpr int NGRP    = (KC + KGRP - 1) / KGRP;
    constexpr int G       = 4 / CSPLIT;          // V chunks per wave per PV pair
    constexpr int QCH     = BROWS * 72;          // LDS shorts per staged Q chunk
    constexpr int QOFF    = KGRP * 4608;

    __shared__ ushort_t smem[SLABS * 4608 + 4 * 1152];
    const int tid  = threadIdx.x;
    const int lane = tid & 63;
    const int w    = tid >> 6;
    const int l15  = lane & 15;
    const int quad = lane >> 4;

    const int bq = blockIdx.x / SPLIT;
    const int sp = blockIdx.x % SPLIT;
    const int b  = bq / QB;
    const int qb = bq % QB;
    const int ls  = w / CSPLIT;       // stripe within block
    const int ch2 = w % CSPLIT;       // channel part
    const int i0 = qb * BROWS + ls * 16;
    const long po = (long)(b * (N / 16) + qb * STRIPES + ls) * SPLIT + sp;
    ushort_t* Pw = smem + SLABS * 4608 + w * 1152;

    half8 qf[NKS];
    if constexpr (QREG) {
        const ushort_t* q1 = Qh + ((long)(b * N + i0 + l15)) * Cc + quad * 8;
#pragma unroll
        for (int ks = 0; ks < NKS; ++ks) qf[ks] = ldh(q1 + ks * 32);
    }

    float m_r[4], l_l[4], mw = -1e30f;
    f32x4 Mac[CTCW], Sac[CTCW];
#pragma unroll
    for (int r = 0; r < 4; ++r) { m_r[r] = -1e30f; l_l[r] = 0.f; }
#pragma unroll
    for (int ct = 0; ct < CTCW; ++ct)
#pragma unroll
        for (int r = 0; r < 4; ++r) { Mac[ct][r] = 0.f; Sac[ct][r] = 0.f; }

    for (int kt = sp * NKT; kt < sp * NKT + NKT; ++kt) {
        const long krow = (long)b * N + kt * 64;

        f32x4 S[4];
#pragma unroll
        for (int ct = 0; ct < 4; ++ct)
#pragma unroll
            for (int r = 0; r < 4; ++r) S[ct][r] = 0.f;

        // ---- QK ----
#pragma unroll
        for (int grp = 0; grp < NGRP; ++grp) {
            const int g0 = grp * KGRP;
            const int gn = (KC - g0 < KGRP) ? (KC - g0) : KGRP;
            __syncthreads();
#pragma unroll
            for (int j = 0; j < KGRP; ++j) if (j < gn) {
                stage64(Kh, krow, Cc, (g0 + j) * 64, smem + j * 4608, tid);
                if constexpr (!QREG)
                    stageQ<BROWS>(Qh, (long)b * N + qb * BROWS, Cc, (g0 + j) * 64,
                                  smem + QOFF + j * QCH, tid);
            }
            __syncthreads();
#pragma unroll
            for (int j = 0; j < KGRP; ++j) if (j < gn) {
#pragma unroll
                for (int ks = 0; ks < 2; ++ks) {
                    half8 a;
                    if constexpr (QREG) a = qf[(g0 + j) * 2 + ks];
                    else a = ldh(smem + QOFF + j * QCH +
                                 (ls * 16 + l15) * 72 + ks * 32 + quad * 8);
#pragma unroll
                    for (int ct = 0; ct < 4; ++ct) {
                        half8 bf = ldh(smem + j * 4608 +
                                       (ct * 16 + l15) * 72 + ks * 32 + quad * 8);
                        S[ct] = MFMAH(a, bf, S[ct]);
                    }
                }
            }
        }

        // ---- online softmax, lazy base (rescale only when band exceeded) ----
        float tmax = S[0][0];
#pragma unroll
        for (int ct = 0; ct < 4; ++ct)
#pragma unroll
            for (int r = 0; r < 4; ++r) tmax = fmaxf(tmax, S[ct][r]);
#pragma unroll
        for (int off = 1; off <= 32; off <<= 1)
            tmax = fmaxf(tmax, __shfl_xor(tmax, off, 64));

        if (tmax > mw + 10.f) {               // rare (first tile + ~2-3 more)
            float rm[4];
#pragma unroll
            for (int r = 0; r < 4; ++r)
                rm[r] = fmaxf(fmaxf(S[0][r], S[1][r]), fmaxf(S[2][r], S[3][r]));
#pragma unroll
            for (int off = 1; off <= 8; off <<= 1)
#pragma unroll
                for (int r = 0; r < 4; ++r)
                    rm[r] = fmaxf(rm[r], __shfl_xor(rm[r], off, 64));
#pragma unroll
            for (int r = 0; r < 4; ++r) {
                float mn = fmaxf(m_r[r], rm[r]);
                float corr = __expf(m_r[r] - mn);
                m_r[r] = mn;
                l_l[r] *= corr;
#pragma unroll
                for (int ct = 0; ct < CTCW; ++ct) { Mac[ct][r] *= corr; Sac[ct][r] *= corr; }
            }
            float t = fminf(fminf(m_r[0], m_r[1]), fminf(m_r[2], m_r[3]));
            t = fminf(t, __shfl_xor(t, 16, 64));
            t = fminf(t, __shfl_xor(t, 32, 64));
            mw = t;
        }

#pragma unroll
        for (int ct = 0; ct < 4; ++ct)
#pragma unroll
            for (int r = 0; r < 4; ++r) {
                float p = __expf(S[ct][r] - m_r[r]);   // p <= e^10, f16-safe
                l_l[r] += p;
                Pw[(quad * 4 + r) * 72 + ct * 16 + l15] = f16_bits(p);
            }

        half8 pf0 = ldh(Pw + l15 * 72 + 0  + quad * 8);
        half8 pf1 = ldh(Pw + l15 * 72 + 32 + quad * 8);

        // ---- PV / PV^2 (V^2 squared in-register) ----
#pragma unroll
        for (int g = 0; g < VCW; g += G) {
            __syncthreads();
#pragma unroll
            for (int s = 0; s < 4; ++s) {
                const int h = s / G, j = s % G;
                stage64(Vth, (long)b * C + (h * VCW + g + j) * 64, N, kt * 64,
                        smem + s * 4608, tid);
            }
            __syncthreads();
#pragma unroll
            for (int ks = 0; ks < 2; ++ks) {
                half8 pf = ks ? pf1 : pf0;
#pragma unroll
                for (int j = 0; j < G; ++j)
#pragma unroll
                    for (int ct = 0; ct < 4; ++ct) {
                        const int vo = (ct * 16 + l15) * 72 + ks * 32 + quad * 8;
                        half8 vh = ldh(smem + (ch2 * G + j) * 4608 + vo);
                        half8 uh = vh * vh;
                        const int ci = (g + j) * 4 + ct;
                        Mac[ci] = MFMAH(pf, vh, Mac[ci]);
                        Sac[ci] = MFMAH(pf, uh, Sac[ci]);
                    }
            }
        }
    }

    // ---- reduce per-lane l, dump partial state ----
#pragma unroll
    for (int off = 1; off <= 8; off <<= 1)
#pragma unroll
        for (int r = 0; r < 4; ++r) l_l[r] += __shfl_xor(l_l[r], off, 64);

    if (ch2 == 0 && l15 == 0) {
#pragma unroll
        for (int r = 0; r < 4; ++r) {
            Pmo[po * 16 + quad * 4 + r] = m_r[r];
            Plo[po * 16 + quad * 4 + r] = l_l[r];
        }
    }
    const int chb = ch2 * (C / CSPLIT);
#pragma unroll
    for (int ct = 0; ct < CTCW; ++ct)
#pragma unroll
        for (int r = 0; r < 4; ++r) {
            long idx = (po * 16 + quad * 4 + r) * C + chb + ct * 16 + l15;
            PMo[idx] = Mac[ct][r];
            PSo[idx] = Sac[ct][r];
        }
}

// ---------------------------------------------------------------------------
// Combine: merge SPLIT flash partials per 16-row stripe, fused epilogue + MSE.
// ---------------------------------------------------------------------------
template<int C, int SPLIT>
__global__ void __launch_bounds__(256) combine_aat(
    const float* __restrict__ Pm, const float* __restrict__ Pl,
    const float* __restrict__ PM, const float* __restrict__ PS,
    const float* __restrict__ CT, const float* __restrict__ CS,
    const float* __restrict__ cmean, const float* __restrict__ crstd,
    float* __restrict__ loss, int N)
{
    __shared__ float wS[SPLIT][16];
    __shared__ float invL[16];
    __shared__ float red[4];
    const int pi = blockIdx.x;
    const int nb = N / 16;
    const int b  = pi / nb;
    const long g0 = (long)b * N + (long)(pi % nb) * 16;
    const int tid = threadIdx.x;

    if (tid < 16) {
        float m = -1e30f;
#pragma unroll
        for (int s = 0; s < SPLIT; ++s)
            m = fmaxf(m, Pm[((long)pi * SPLIT + s) * 16 + tid]);
        float L = 0.f;
#pragma unroll
        for (int s = 0; s < SPLIT; ++s) {
            float e = __expf(Pm[((long)pi * SPLIT + s) * 16 + tid] - m);
            wS[s][tid] = e;
            L = fmaf(e, Pl[((long)pi * SPLIT + s) * 16 + tid], L);
        }
        invL[tid] = 1.f / L;
    }
    __syncthreads();

    float acc = 0.f;
    for (int e = tid; e < 16 * C; e += 256) {
        const int r  = e / C;
        const int ch = e % C;
        float Ms = 0.f, Ss = 0.f;
#pragma unroll
        for (int s = 0; s < SPLIT; ++s) {
            const long q = (((long)pi * SPLIT + s) * 16 + r) * C + ch;
            Ms = fmaf(wS[s][r], PM[q], Ms);
            Ss = fmaf(wS[s][r], PS[q], Ss);
        }
        const float M  = Ms * invL[r];
        const float S2 = Ss * invL[r] - M * M;
        const float S  = sqrtf(fmaxf(S2, EPS_VAR));
        const float nc = (CT[(g0 + r) * C + ch] - cmean[b * C + ch]) * crstd[b * C + ch];
        const float d  = CS[(g0 + r) * C + ch] - (S * nc + M);
        acc = fmaf(d, d, acc);
    }
#pragma unroll
    for (int off = 1; off <= 32; off <<= 1) acc += __shfl_xor(acc, off, 64);
    if ((tid & 63) == 0) red[tid >> 6] = acc;
    __syncthreads();
    if (tid == 0) atomicAdd(loss, red[0] + red[1] + red[2] + red[3]);
}

// ---------------------------------------------------------------------------
// Fallback scalar flash kernel (only if ws_size too small)
// ---------------------------------------------------------------------------
template<int CCL, int CL, int NQ>
__global__ void __launch_bounds__(256) flash_aat(
    const float* __restrict__ Q, const float* __restrict__ K, const float* __restrict__ V,
    const float* __restrict__ CT, const float* __restrict__ CS,
    const float* __restrict__ qmean, const float* __restrict__ qrstd,
    const float* __restrict__ kmean, const float* __restrict__ krstd,
    const float* __restrict__ cmean, const float* __restrict__ crstd,
    float* __restrict__ loss, int N)
{
    constexpr int CC   = CCL * 64;
    constexpr int C    = CL * 64;
    constexpr int ROWS = 4 * NQ;
    const int lane = threadIdx.x & 63;
    const int wave = threadIdx.x >> 6;
    const int rowBlocks = N / ROWS;
    const int b  = blockIdx.x / rowBlocks;
    const int rb = blockIdx.x % rowBlocks;
    const int i0 = rb * ROWS + wave * NQ;

    float kmu[CCL], krs[CCL];
#pragma unroll
    for (int t = 0; t < CCL; ++t) {
        int ch = lane + 64 * t;
        kmu[t] = kmean[b * CC + ch];
        krs[t] = krstd[b * CC + ch];
    }
    float q[NQ][CCL];
#pragma unroll
    for (int qi = 0; qi < NQ; ++qi) {
        long base = (long)(b * N + i0 + qi) * CC;
#pragma unroll
        for (int t = 0; t < CCL; ++t) {
            int ch = lane + 64 * t;
            q[qi][t] = (Q[base + ch] - qmean[b * CC + ch]) * qrstd[b * CC + ch];
        }
    }
    float mval[NQ], lsum[NQ];
    float Macc[NQ][CL], Sacc[NQ][CL];
#pragma unroll
    for (int qi = 0; qi < NQ; ++qi) {
        mval[qi] = -1e30f; lsum[qi] = 0.f;
#pragma unroll
        for (int t = 0; t < CL; ++t) { Macc[qi][t] = 0.f; Sacc[qi][t] = 0.f; }
    }
    for (int j = 0; j < N; ++j) {
        long kb = (long)(b * N + j) * CC;
        float dot[NQ];
#pragma unroll
        for (int qi = 0; qi < NQ; ++qi) dot[qi] = 0.f;
#pragma unroll
        for (int t = 0; t < CCL; ++t) {
            float kv = (K[kb + lane + 64 * t] - kmu[t]) * krs[t];
#pragma unroll
            for (int qi = 0; qi < NQ; ++qi) dot[qi] = fmaf(q[qi][t], kv, dot[qi]);
        }
#pragma unroll
        for (int off = 32; off > 0; off >>= 1)
#pragma unroll
            for (int qi = 0; qi < NQ; ++qi) dot[qi] += __shfl_xor(dot[qi], off, 64);
        long vb = (long)(b * N + j) * C;
        float vv[CL];
#pragma unroll
        for (int t = 0; t < CL; ++t) vv[t] = V[vb + lane + 64 * t];
#pragma unroll
        for (int qi = 0; qi < NQ; ++qi) {
            float s = dot[qi];
            float p;
            if (s > mval[qi]) {
                float cr2 = __expf(mval[qi] - s);
                lsum[qi] *= cr2;
#pragma unroll
                for (int t = 0; t < CL; ++t) { Macc[qi][t] *= cr2; Sacc[qi][t] *= cr2; }
                mval[qi] = s; p = 1.f;
            } else p = __expf(s - mval[qi]);
            lsum[qi] += p;
#pragma unroll
            for (int t = 0; t < CL; ++t) {
                float pv = p * vv[t];
                Macc[qi][t] += pv;
                Sacc[qi][t] = fmaf(pv, vv[t], Sacc[qi][t]);
            }
        }
    }
    float acc = 0.f;
#pragma unroll
    for (int qi = 0; qi < NQ; ++qi) {
        float inv_l = 1.f / lsum[qi];
        long base = (long)(b * N + i0 + qi) * C;
#pragma unroll
        for (int t = 0; t < CL; ++t) {
            int ch = lane + 64 * t;
            float M  = Macc[qi][t] * inv_l;
            float S2 = Sacc[qi][t] * inv_l - M * M;
            float S  = sqrtf(fmaxf(S2, EPS_VAR));
            float nc = (CT[base + ch] - cmean[b * C + ch]) * crstd[b * C + ch];
            float d  = CS[base + ch] - (S * nc + M);
            acc = fmaf(d, d, acc);
        }
    }
#pragma unroll
    for (int off = 32; off > 0; off >>= 1) acc += __shfl_xor(acc, off, 64);
    if (lane == 0) atomicAdd(loss, acc);
}

__global__ void combine_loss(const float* __restrict__ lp, float* __restrict__ out,
                             float s0, float s1, float s2)
{
    out[0] = lp[0] * s0 + lp[1] * s1 + lp[2] * s2;
}

// ---------------------------------------------------------------------------
extern "C" void kernel_launch(void* const* d_in, const int* in_sizes, int n_in,
                              void* d_out, int out_size, void* d_ws, size_t ws_size,
                              hipStream_t stream)
{
    const float* cs2 = (const float*)d_in[0];
    const float* c2  = (const float*)d_in[1];
    const float* s2v = (const float*)d_in[2];
    const float* cc2 = (const float*)d_in[3];
    const float* sc2 = (const float*)d_in[4];
    const float* cs3 = (const float*)d_in[5];
    const float* c3  = (const float*)d_in[6];
    const float* s3v = (const float*)d_in[7];
    const float* cc3 = (const float*)d_in[8];
    const float* sc3 = (const float*)d_in[9];
    const float* cs4 = (const float*)d_in[10];
    const float* c4  = (const float*)d_in[11];
    const float* s4v = (const float*)d_in[12];
    const float* cc4 = (const float*)d_in[13];
    const float* sc4 = (const float*)d_in[14];

    const int B = 4;
    float* ws = (float*)d_ws;
    size_t fo = 0;
    auto allocF = [&](size_t n) { float* p = ws + fo; fo += n; return p; };

    float* lossp = allocF(4);
    float* c2m = allocF(B * 256);  float* c2r = allocF(B * 256);
    float* q2m = allocF(B * 448);  float* q2r = allocF(B * 448);
    float* k2m = allocF(B * 448);  float* k2r = allocF(B * 448);
    float* c3m = allocF(B * 512);  float* c3r = allocF(B * 512);
    float* q3m = allocF(B * 960);  float* q3r = allocF(B * 960);
    float* k3m = allocF(B * 960);  float* k3r = allocF(B * 960);
    float* c4m = allocF(B * 512);  float* c4r = allocF(B * 512);
    float* q4m = allocF(B * 1472); float* q4r = allocF(B * 1472);
    float* k4m = allocF(B * 1472); float* k4r = allocF(B * 1472);
    size_t zeroBytes = fo * sizeof(float);

    // partial-state buffers (shared across scales; stream-ordered reuse)
    float* Pm = allocF(32768);
    float* Pl = allocF(32768);
    float* PM = allocF(8388608);
    float* PS = allocF(8388608);

    // fp16 arena (16B aligned), reused per scale
    size_t arenaOff = ((fo * 4 + 15) & ~(size_t)15) / 2;
    ushort_t* arena = (ushort_t*)d_ws + arenaOff;
    const size_t arenaShorts = 18874400;   // max per-scale need (scale 2)
    size_t need = arenaOff * 2 + arenaShorts * 2;
    const bool fast = (ws_size >= need);

    hipMemsetAsync(d_ws, 0, zeroBytes, stream);

    auto stats = [&](const float* x, float* sm, float* sq, int N, int Cn) {
        int chG  = (Cn + 255) / 256;
        int nPer = 256;
        int nG   = (N + nPer - 1) / nPer;
        hipLaunchKernelGGL(stat_partial, dim3(B * chG * nG), dim3(256), 0, stream,
                           x, sm, sq, N, Cn, chG, nG, nPer);
        int total = B * Cn;
        hipLaunchKernelGGL(stat_finalize, dim3((total + 255) / 256), dim3(256), 0, stream,
                           sm, sq, total, 1.0f / (float)N);
    };

    stats(c2,  c2m, c2r, 4096, 256);
    stats(cc2, q2m, q2r, 4096, 448);
    stats(sc2, k2m, k2r, 4096, 448);
    stats(c3,  c3m, c3r, 1024, 512);
    stats(cc3, q3m, q3r, 1024, 960);
    stats(sc3, k3m, k3r, 1024, 960);
    stats(c4,  c4m, c4r, 256, 512);
    stats(cc4, q4m, q4r, 256, 1472);
    stats(sc4, k4m, k4r, 256, 1472);

    if (fast) {
        // ---- scale 2: N=4096, Cc=448, C=256, CSPLIT=1 (QREG), SPLIT=2,
        //      SLABS=7 (whole K-tile staged in one barrier pair) ----
        {
            size_t o = 0;
            auto aU = [&](size_t n) { ushort_t* p = arena + o; o += (n + 7) & ~(size_t)7; return p; };
            ushort_t *qh = aU((size_t)B*4096*448), *kh = aU((size_t)B*4096*448);
            ushort_t *vh = aU((size_t)B*4096*256);
            hipLaunchKernelGGL(norm_f16, dim3(B*4096), dim3(256), 0, stream, cc2, q2m, q2r, qh, 4096, 448);
            hipLaunchKernelGGL(norm_f16, dim3(B*4096), dim3(256), 0, stream, sc2, k2m, k2r, kh, 4096, 448);
            hipLaunchKernelGGL((vsplit_t<512>), dim3(B*(256/64)*(4096/512)), dim3(256), 0, stream,
                               s2v, vh, 4096, 256);
            hipLaunchKernelGGL((flash_mfma<448, 256, 4096, 1, true, 2, 7, 7>),
                               dim3(B*(4096/64)*2), dim3(256), 0, stream,
                               qh, kh, vh, Pm, Pl, PM, PS);
            hipLaunchKernelGGL((combine_aat<256, 2>), dim3(B*4096/16), dim3(256), 0, stream,
                               Pm, Pl, PM, PS, c2, cs2, c2m, c2r, &lossp[0], 4096);
        }
        // ---- scale 3: N=1024, Cc=960, C=512, CSPLIT=2, SPLIT=4, SLABS=4 ----
        {
            size_t o = 0;
            auto aU = [&](size_t n) { ushort_t* p = arena + o; o += (n + 7) & ~(size_t)7; return p; };
            ushort_t *qh = aU((size_t)B*1024*960), *kh = aU((size_t)B*1024*960);
            ushort_t *vh = aU((size_t)B*1024*512);
            hipLaunchKernelGGL(norm_f16, dim3(B*1024), dim3(256), 0, stream, cc3, q3m, q3r, qh, 1024, 960);
            hipLaunchKernelGGL(norm_f16, dim3(B*1024), dim3(256), 0, stream, sc3, k3m, k3r, kh, 1024, 960);
            hipLaunchKernelGGL((vsplit_t<512>), dim3(B*(512/64)*(1024/512)), dim3(256), 0, stream,
                               s3v, vh, 1024, 512);
            hipLaunchKernelGGL((flash_mfma<960, 512, 1024, 2, false, 4, 4, 2>),
                               dim3(B*(1024/32)*4), dim3(256), 0, stream,
                               qh, kh, vh, Pm, Pl, PM, PS);
            hipLaunchKernelGGL((combine_aat<512, 4>), dim3(B*1024/16), dim3(256), 0, stream,
                               Pm, Pl, PM, PS, c3, cs3, c3m, c3r, &lossp[1], 1024);
        }
        // ---- scale 4: N=256, Cc=1472, C=512, CSPLIT=4, SPLIT=4, SLABS=4 ----
        {
            size_t o = 0;
            auto aU = [&](size_t n) { ushort_t* p = arena + o; o += (n + 7) & ~(size_t)7; return p; };
            ushort_t *qh = aU((size_t)B*256*1472), *kh = aU((size_t)B*256*1472);
            ushort_t *vh = aU((size_t)B*256*512);
            hipLaunchKernelGGL(norm_f16, dim3(B*256), dim3(256), 0, stream, cc4, q4m, q4r, qh, 256, 1472);
            hipLaunchKernelGGL(norm_f16, dim3(B*256), dim3(256), 0, stream, sc4, k4m, k4r, kh, 256, 1472);
            hipLaunchKernelGGL((vsplit_t<256>), dim3(B*(512/64)*(256/256)), dim3(256), 0, stream,
                               s4v, vh, 256, 512);
            hipLaunchKernelGGL((flash_mfma<1472, 512, 256, 4, false, 4, 4, 2>),
                               dim3(B*(256/16)*4), dim3(256), 0, stream,
                               qh, kh, vh, Pm, Pl, PM, PS);
            hipLaunchKernelGGL((combine_aat<512, 4>), dim3(B*256/16), dim3(256), 0, stream,
                               Pm, Pl, PM, PS, c4, cs4, c4m, c4r, &lossp[2], 256);
        }
    } else {
        hipLaunchKernelGGL((flash_aat<7, 4, 4>), dim3(B * 4096 / 16), dim3(256), 0, stream,
                           cc2, sc2, s2v, c2, cs2, q2m, q2r, k2m, k2r, c2m, c2r, &lossp[0], 4096);
        hipLaunchKernelGGL((flash_aat<15, 8, 2>), dim3(B * 1024 / 8), dim3(256), 0, stream,
                           cc3, sc3, s3v, c3, cs3, q3m, q3r, k3m, k3r, c3m, c3r, &lossp[1], 1024);
        hipLaunchKernelGGL((flash_aat<23, 8, 2>), dim3(B * 256 / 8), dim3(256), 0, stream,
                           cc4, sc4, s4v, c4, cs4, q4m, q4r, k4m, k4r, c4m, c4r, &lossp[2], 256);
    }

    hipLaunchKernelGGL(combine_loss, dim3(1), dim3(1), 0, stream,
                       lossp, (float*)d_out,
                       1.0f / (4.0f * 4096.0f * 256.0f),
                       1.0f / (4.0f * 1024.0f * 512.0f),
                       1.0f / (4.0f * 256.0f * 512.0f));
}